// Round 1
// baseline (3733.788 us; speedup 1.0000x reference)
//
#include <hip/hip_runtime.h>
#include <math.h>
#include <cstddef>

// ---- problem constants ----
#define RTOK 4096   // BS * NMASK rows
#define CDIM 256
#define NHEAD 16
#define DHEAD 16
#define SEQ 1024
#define BSZ 4

#define ACT_NONE 0
#define ACT_GELU 1
#define ACT_RELU 2
#define ACT_SIG  3

__device__ __forceinline__ float gelu_erf(float x) {
    return 0.5f * x * (1.0f + erff(x * 0.70710678118654752f));
}

// ---------------------------------------------------------------------------
// Fused patch-embed + pos-embed + cls + mask-gather.
// One block per output row (b*1024+t), one thread per channel c.
// ---------------------------------------------------------------------------
__global__ __launch_bounds__(256) void embed_kernel(
    const float* __restrict__ x,           // [4,3,128,128]
    const int*   __restrict__ mask_index,  // [4,1024]
    const float* __restrict__ Wp,          // [256,3,2,2]
    const float* __restrict__ bp,          // [256]
    const float* __restrict__ cls,         // [256]
    float* __restrict__ out)               // [4096,256]
{
    int row = blockIdx.x;        // 0..4095
    int b = row >> 10;
    int c = threadIdx.x;         // 0..255
    int idx = mask_index[row];   // uniform per block
    if (idx == 0) {
        out[(size_t)row * 256 + c] = cls[c];
        return;
    }
    int p  = idx - 1;
    int ph = p >> 6;   // h index 0..63
    int pw = p & 63;   // w index 0..63

    __shared__ float xs[12];
    if (c < 12) {
        int ch = c >> 2, r = (c >> 1) & 1, q = c & 1;
        xs[c] = x[(((size_t)b * 3 + ch) * 128 + (ph * 2 + r)) * 128 + (pw * 2 + q)];
    }
    __syncthreads();

    float acc = bp[c];
    #pragma unroll
    for (int t = 0; t < 12; ++t) acc += xs[t] * Wp[c * 12 + t];

    // sincos pos embed (double to match numpy float64 path)
    int part = c >> 6;         // 0: sin(w) 1: cos(w) 2: sin(h) 3: cos(h)
    int cc   = c & 63;
    double omega = exp((double)cc * -0.14391156831212787); // -ln(10000)/64
    double posv  = (part < 2) ? (double)pw : (double)ph;
    double a     = posv * omega;
    double e     = ((part & 1) == 0) ? sin(a) : cos(a);
    out[(size_t)row * 256 + c] = acc + (float)e;
}

// ---------------------------------------------------------------------------
// Generic tiled fp32 GEMM: C[M,N] = act(A[M,K] @ W[K,N] + bias) (+ residual)
// 64x64 tile, BK=16, 256 threads, 4x4 per thread. M % 64 == 0, K % 16 == 0.
// ---------------------------------------------------------------------------
template<int ACT, bool RES>
__global__ __launch_bounds__(256) void gemm_kernel(
    const float* __restrict__ A, const float* __restrict__ W,
    const float* __restrict__ bias, const float* __restrict__ Rsd,
    float* __restrict__ C, int M, int N, int K)
{
    __shared__ float As[64][17];
    __shared__ float Bs[16][65];
    int bx = blockIdx.x, by = blockIdx.y;
    int tx = threadIdx.x, ty = threadIdx.y;
    int tid = ty * 16 + tx;
    int row0 = by * 64, col0 = bx * 64;
    float acc[4][4] = {};

    for (int kb = 0; kb < K; kb += 16) {
        #pragma unroll
        for (int l = tid; l < 1024; l += 256) {
            int r = l >> 4, c = l & 15;
            As[r][c] = A[(size_t)(row0 + r) * K + kb + c];
        }
        #pragma unroll
        for (int l = tid; l < 1024; l += 256) {
            int r = l >> 6, c = l & 63;
            int col = col0 + c;
            Bs[r][c] = (col < N) ? W[(size_t)(kb + r) * N + col] : 0.0f;
        }
        __syncthreads();
        #pragma unroll
        for (int kk = 0; kk < 16; ++kk) {
            float a[4], bb[4];
            #pragma unroll
            for (int i = 0; i < 4; ++i) a[i] = As[ty * 4 + i][kk];
            #pragma unroll
            for (int j = 0; j < 4; ++j) bb[j] = Bs[kk][tx * 4 + j];
            #pragma unroll
            for (int i = 0; i < 4; ++i)
                #pragma unroll
                for (int j = 0; j < 4; ++j)
                    acc[i][j] += a[i] * bb[j];
        }
        __syncthreads();
    }

    #pragma unroll
    for (int i = 0; i < 4; ++i) {
        int row = row0 + ty * 4 + i;
        #pragma unroll
        for (int j = 0; j < 4; ++j) {
            int col = col0 + tx * 4 + j;
            if (col < N) {
                float v = acc[i][j] + bias[col];
                if (ACT == ACT_GELU) v = gelu_erf(v);
                else if (ACT == ACT_RELU) v = fmaxf(v, 0.0f);
                else if (ACT == ACT_SIG)  v = 1.0f / (1.0f + expf(-v));
                if (RES) v += Rsd[(size_t)row * N + col];
                C[(size_t)row * N + col] = v;
            }
        }
    }
}

// ---------------------------------------------------------------------------
// mixed = sum_n softmax(node_w[:cnt]/0.01)[n] * feat_n
// ---------------------------------------------------------------------------
__global__ __launch_bounds__(256) void mix_kernel(
    const float* p0, const float* p1, const float* p2, const float* p3,
    const float* p4, const float* p5, const float* p6, const float* p7,
    const float* __restrict__ node_w, int cnt,
    float* __restrict__ out, int n)
{
    int i = blockIdx.x * 256 + threadIdx.x;
    if (i >= n) return;
    float w[8];
    float mx = -1e30f;
    for (int t = 0; t < cnt; ++t) { w[t] = node_w[t] * 100.0f; mx = fmaxf(mx, w[t]); }
    float s = 0.0f;
    for (int t = 0; t < cnt; ++t) { w[t] = expf(w[t] - mx); s += w[t]; }
    float inv = 1.0f / s;
    const float* ps[8] = {p0, p1, p2, p3, p4, p5, p6, p7};
    float v = 0.0f;
    for (int t = 0; t < cnt; ++t) v += w[t] * inv * ps[t][i];
    out[i] = v;
}

// dst *= src  (channel-attention gate)
__global__ __launch_bounds__(256) void ewmul_kernel(
    float* __restrict__ dst, const float* __restrict__ src, int n)
{
    int i = blockIdx.x * 256 + threadIdx.x;
    if (i < n) dst[i] *= src[i];
}

// ---------------------------------------------------------------------------
// Row LayerNorm (exact two-pass), in-place safe. One block per row.
// ---------------------------------------------------------------------------
__global__ __launch_bounds__(256) void ln_kernel(
    const float* __restrict__ in, float* __restrict__ out,
    const float* __restrict__ g, const float* __restrict__ bb, int N)
{
    __shared__ float sm[4];
    size_t row = blockIdx.x;
    const float* xr = in + row * N;
    int lane = threadIdx.x & 63, wid = threadIdx.x >> 6;

    float s = 0.0f;
    for (int i = threadIdx.x; i < N; i += 256) s += xr[i];
    #pragma unroll
    for (int off = 32; off > 0; off >>= 1) s += __shfl_down(s, off, 64);
    if (lane == 0) sm[wid] = s;
    __syncthreads();
    float mu = (sm[0] + sm[1] + sm[2] + sm[3]) / N;
    __syncthreads();

    float s2 = 0.0f;
    for (int i = threadIdx.x; i < N; i += 256) { float d = xr[i] - mu; s2 += d * d; }
    #pragma unroll
    for (int off = 32; off > 0; off >>= 1) s2 += __shfl_down(s2, off, 64);
    if (lane == 0) sm[wid] = s2;
    __syncthreads();
    float var = (sm[0] + sm[1] + sm[2] + sm[3]) / N;
    float rstd = rsqrtf(var + 1e-5f);

    for (int i = threadIdx.x; i < N; i += 256)
        out[row * N + i] = (xr[i] - mu) * rstd * g[i] + bb[i];
}

// ---------------------------------------------------------------------------
// Fused attention: per-head-dim LN on q/k + flash-style online softmax.
// grid (qtile=4, head=16, batch=4), 256 threads = 1 query/thread.
// LDS: 256 keys x (16 k + 16 v) per chunk.
// ---------------------------------------------------------------------------
__global__ __launch_bounds__(256) void attn_kernel(
    const float* __restrict__ qkv,   // [4096, 768]: q|k|v per row
    const float* __restrict__ nqg, const float* __restrict__ nqb,
    const float* __restrict__ nkg, const float* __restrict__ nkb,
    float* __restrict__ out)         // [4096, 256]
{
    int qt = blockIdx.x, h = blockIdx.y, b = blockIdx.z;
    int tid = threadIdx.x;
    __shared__ float kv[256][36];    // [key][0:16 k_ln | 16:32 v], padded

    int qrow = qt * 256 + tid;       // 0..1023 within batch
    const float* qp = qkv + ((size_t)(b * 1024 + qrow)) * 768 + h * 16;

    // q + LN + fold 1/sqrt(DH)
    float q[16];
    float mu = 0.0f;
    #pragma unroll
    for (int d = 0; d < 16; ++d) { q[d] = qp[d]; mu += q[d]; }
    mu *= (1.0f / 16.0f);
    float var = 0.0f;
    #pragma unroll
    for (int d = 0; d < 16; ++d) { float t = q[d] - mu; var += t * t; }
    var *= (1.0f / 16.0f);
    float rstd = rsqrtf(var + 1e-5f);
    #pragma unroll
    for (int d = 0; d < 16; ++d) q[d] = ((q[d] - mu) * rstd * nqg[d] + nqb[d]) * 0.25f;

    float mrun = -1e30f, l = 0.0f;
    float acc[16] = {};

    for (int chunk = 0; chunk < 4; ++chunk) {
        __syncthreads();
        // thread tid loads & LN-normalizes key row (chunk*256 + tid)
        int krow = chunk * 256 + tid;
        const float* kp = qkv + ((size_t)(b * 1024 + krow)) * 768 + 256 + h * 16;
        float kr[16];
        float kmu = 0.0f;
        #pragma unroll
        for (int d = 0; d < 16; ++d) { kr[d] = kp[d]; kmu += kr[d]; }
        kmu *= (1.0f / 16.0f);
        float kvar = 0.0f;
        #pragma unroll
        for (int d = 0; d < 16; ++d) { float t = kr[d] - kmu; kvar += t * t; }
        kvar *= (1.0f / 16.0f);
        float krstd = rsqrtf(kvar + 1e-5f);
        #pragma unroll
        for (int d = 0; d < 16; ++d) kv[tid][d] = (kr[d] - kmu) * krstd * nkg[d] + nkb[d];
        const float* vp = kp + 256;
        #pragma unroll
        for (int d = 0; d < 16; ++d) kv[tid][16 + d] = vp[d];
        __syncthreads();

        for (int kk = 0; kk < 256; ++kk) {
            float s = 0.0f;
            #pragma unroll
            for (int d = 0; d < 16; ++d) s += q[d] * kv[kk][d];
            float mnew = fmaxf(mrun, s);
            float corr = expf(mrun - mnew);
            float e    = expf(s - mnew);
            l = l * corr + e;
            #pragma unroll
            for (int d = 0; d < 16; ++d) acc[d] = acc[d] * corr + e * kv[kk][16 + d];
            mrun = mnew;
        }
    }

    float invl = 1.0f / l;
    float* op = out + ((size_t)(b * 1024 + qrow)) * 256 + h * 16;
    #pragma unroll
    for (int d = 0; d < 16; ++d) op[d] = acc[d] * invl;
}

// ---------------------------------------------------------------------------
static void launch_gemm(const float* A, const float* W, const float* bias,
                        const float* res, float* C, int M, int N, int K,
                        int act, hipStream_t stream)
{
    dim3 grid((N + 63) / 64, M / 64), block(16, 16);
    if (res) {
        gemm_kernel<ACT_NONE, true><<<grid, block, 0, stream>>>(A, W, bias, res, C, M, N, K);
        return;
    }
    switch (act) {
        case ACT_GELU: gemm_kernel<ACT_GELU, false><<<grid, block, 0, stream>>>(A, W, bias, nullptr, C, M, N, K); break;
        case ACT_RELU: gemm_kernel<ACT_RELU, false><<<grid, block, 0, stream>>>(A, W, bias, nullptr, C, M, N, K); break;
        case ACT_SIG:  gemm_kernel<ACT_SIG,  false><<<grid, block, 0, stream>>>(A, W, bias, nullptr, C, M, N, K); break;
        default:       gemm_kernel<ACT_NONE, false><<<grid, block, 0, stream>>>(A, W, bias, nullptr, C, M, N, K); break;
    }
}

extern "C" void kernel_launch(void* const* d_in, const int* in_sizes, int n_in,
                              void* d_out, int out_size, void* d_ws, size_t ws_size,
                              hipStream_t stream)
{
    const float* x          = (const float*)d_in[0];
    const int*   mask_index = (const int*)  d_in[1];
    const float* Wp         = (const float*)d_in[2];
    const float* bp         = (const float*)d_in[3];
    const float* cls        = (const float*)d_in[4];
    const float* qkv_w      = (const float*)d_in[5];
    const float* qkv_b      = (const float*)d_in[6];
    const float* proj_w     = (const float*)d_in[7];
    const float* proj_b     = (const float*)d_in[8];
    const float* nq_g       = (const float*)d_in[9];
    const float* nq_b       = (const float*)d_in[10];
    const float* nk_g       = (const float*)d_in[11];
    const float* nk_b       = (const float*)d_in[12];
    const float* conv_w     = (const float*)d_in[13];
    const float* conv_b     = (const float*)d_in[14];
    const float* ca1_w      = (const float*)d_in[15];
    const float* ca1_b      = (const float*)d_in[16];
    const float* ca2_w      = (const float*)d_in[17];
    const float* ca2_b      = (const float*)d_in[18];
    const float* mlp1_w     = (const float*)d_in[19];
    const float* mlp1_b     = (const float*)d_in[20];
    const float* mlp2_w     = (const float*)d_in[21];
    const float* mlp2_b     = (const float*)d_in[22];
    const float* node_w     = (const float*)d_in[23];
    const float* ln0_g      = (const float*)d_in[24];
    const float* ln0_b      = (const float*)d_in[25];
    const float* h1_w       = (const float*)d_in[26];
    const float* h1_b       = (const float*)d_in[27];
    const float* ln1_g      = (const float*)d_in[28];
    const float* ln1_b      = (const float*)d_in[29];
    const float* h2_w       = (const float*)d_in[30];
    const float* h2_b       = (const float*)d_in[31];
    const float* ln2_g      = (const float*)d_in[32];
    const float* ln2_b      = (const float*)d_in[33];
    const float* h3_w       = (const float*)d_in[34];
    const float* h3_b       = (const float*)d_in[35];
    const float* pr_w       = (const float*)d_in[36];
    const float* pr_b       = (const float*)d_in[37];
    float* out = (float*)d_out;
    float* ws  = (float*)d_ws;

    const size_t RC = (size_t)RTOK * CDIM;   // 1,048,576 floats
    float* F[5];
    for (int i = 0; i < 5; ++i) F[i] = ws + i * RC;   // m, xo0..xo3
    float* O1  = ws + 5  * RC;
    float* O2  = ws + 6  * RC;   // gate, then gate*xl
    float* O4  = ws + 7  * RC;
    float* MIX = ws + 8  * RC;
    float* AO  = ws + 9  * RC;
    float* T1  = ws + 10 * RC;   // [4096,16]
    float* QKV = ws + 11 * RC;   // 3*RC  [4096,768]
    float* T4  = ws + 14 * RC;   // 4*RC  [4096,1024]
    float* HA  = ws + 18 * RC;   // 8*RC  [4096,2048]
    // total 26*RC floats = ~104 MB of d_ws

    // ---- patch embed + pos embed + cls + gather ----
    embed_kernel<<<RTOK, 256, 0, stream>>>(x, mask_index, Wp, bp, cls, F[0]);

    // ---- 4 block iterations ----
    for (int j = 0; j < 4; ++j) {
        const float* xl = F[j];
        // o1 = gelu(xl @ conv_w + b)
        launch_gemm(xl, conv_w + (size_t)j * 256 * 256, conv_b + j * 256, nullptr,
                    O1, RTOK, 256, 256, ACT_GELU, stream);
        // channel attention: t1 = relu(xl@ca1+b); gate = sigmoid(t1@ca2+b); o2 = gate*xl
        launch_gemm(xl, ca1_w + (size_t)j * 256 * 16, ca1_b + j * 16, nullptr,
                    T1, RTOK, 16, 256, ACT_RELU, stream);
        launch_gemm(T1, ca2_w + (size_t)j * 16 * 256, ca2_b + j * 256, nullptr,
                    O2, RTOK, 256, 16, ACT_SIG, stream);
        ewmul_kernel<<<(int)(RC / 256), 256, 0, stream>>>(O2, xl, (int)RC);
        // o4 = gelu(xl@mlp1+b)@mlp2+b
        launch_gemm(xl, mlp1_w + (size_t)j * 256 * 1024, mlp1_b + j * 1024, nullptr,
                    T4, RTOK, 1024, 256, ACT_GELU, stream);
        launch_gemm(T4, mlp2_w + (size_t)j * 1024 * 256, mlp2_b + j * 256, nullptr,
                    O4, RTOK, 256, 1024, ACT_NONE, stream);
        // mixed = softmax(node_w[j,:5+j]/0.01) . [F0..Fj, o1, o2, xl, o4]
        const float* ps[8] = {nullptr, nullptr, nullptr, nullptr,
                              nullptr, nullptr, nullptr, nullptr};
        int cnt = 0;
        for (int t = 0; t <= j; ++t) ps[cnt++] = F[t];
        ps[cnt++] = O1; ps[cnt++] = O2; ps[cnt++] = F[j]; ps[cnt++] = O4;
        mix_kernel<<<(int)(RC / 256), 256, 0, stream>>>(
            ps[0], ps[1], ps[2], ps[3], ps[4], ps[5], ps[6], ps[7],
            node_w + j * 8, cnt, MIX, (int)RC);
        // attention
        launch_gemm(MIX, qkv_w + (size_t)j * 256 * 768, qkv_b + j * 768, nullptr,
                    QKV, RTOK, 768, 256, ACT_NONE, stream);
        attn_kernel<<<dim3(4, NHEAD, BSZ), 256, 0, stream>>>(
            QKV, nq_g + j * 16, nq_b + j * 16, nk_g + j * 16, nk_b + j * 16, AO);
        // xo = AO @ proj_w + proj_b + mixed  -> F[j+1]
        launch_gemm(AO, proj_w + (size_t)j * 256 * 256, proj_b + j * 256, MIX,
                    F[j + 1], RTOK, 256, 256, ACT_NONE, stream);
    }

    // ---- predict head ----
    ln_kernel<<<RTOK, 256, 0, stream>>>(F[4], F[4], ln0_g, ln0_b, 256);
    launch_gemm(F[4], h1_w, h1_b, nullptr, HA, RTOK, 2048, 256, ACT_NONE, stream);
    ln_kernel<<<RTOK, 256, 0, stream>>>(HA, HA, ln1_g, ln1_b, 2048);
    launch_gemm(HA, h2_w, h2_b, nullptr, MIX, RTOK, 256, 2048, ACT_NONE, stream);
    ln_kernel<<<RTOK, 256, 0, stream>>>(MIX, MIX, ln2_g, ln2_b, 256);
    launch_gemm(MIX, h3_w, h3_b, nullptr, HA, RTOK, 2048, 256, ACT_NONE, stream);
    launch_gemm(HA, pr_w, pr_b, nullptr, out, RTOK, 512, 2048, ACT_NONE, stream);
}

// Round 2
// 1447.724 us; speedup vs baseline: 2.5791x; 2.5791x over previous
//
#include <hip/hip_runtime.h>
#include <math.h>
#include <cstddef>

// ---- problem constants ----
#define RTOK 4096
#define CDIM 256
#define NHEAD 16
#define DHEAD 16
#define SEQ 1024
#define BSZ 4

#define ACT_NONE 0
#define ACT_GELU 1

typedef short short8 __attribute__((ext_vector_type(8)));
typedef float f32x4  __attribute__((ext_vector_type(4)));

__device__ __forceinline__ float gelu_erf(float x) {
    return 0.5f * x * (1.0f + erff(x * 0.70710678118654752f));
}
__device__ __forceinline__ unsigned short f2b(float f) {
    unsigned u = __float_as_uint(f);
    unsigned r = (u + 0x7FFFu + ((u >> 16) & 1u)) >> 16;
    return (unsigned short)r;
}

// ---------------------------------------------------------------------------
// Weight convert+transpose: in [K,N] fp32 -> out [N,K] bf16. 32x32 LDS tile.
// ---------------------------------------------------------------------------
__global__ __launch_bounds__(256) void wtrans_kernel(
    const float* __restrict__ in, unsigned short* __restrict__ out, int K, int N)
{
    __shared__ float t[32][33];
    int kb = blockIdx.x * 32, nb = blockIdx.y * 32;
    int tx = threadIdx.x, ty = threadIdx.y;   // 32 x 8
    #pragma unroll
    for (int r = 0; r < 4; ++r) {
        int kk = ty * 4 + r;
        t[kk][tx] = in[(size_t)(kb + kk) * N + nb + tx];
    }
    __syncthreads();
    #pragma unroll
    for (int r = 0; r < 4; ++r) {
        int nn = ty * 4 + r;
        out[(size_t)(nb + nn) * K + kb + tx] = f2b(t[tx][nn]);
    }
}

// ---------------------------------------------------------------------------
// Fused patch-embed + pos-embed + cls + mask-gather (fp32 + bf16 outputs).
// ---------------------------------------------------------------------------
__global__ __launch_bounds__(256) void embed_kernel(
    const float* __restrict__ x, const int* __restrict__ mask_index,
    const float* __restrict__ Wp, const float* __restrict__ bp,
    const float* __restrict__ cls,
    float* __restrict__ out, unsigned short* __restrict__ outb)
{
    int row = blockIdx.x;
    int b = row >> 10;
    int c = threadIdx.x;
    int idx = mask_index[row];
    if (idx == 0) {
        float v = cls[c];
        out[(size_t)row * 256 + c] = v;
        outb[(size_t)row * 256 + c] = f2b(v);
        return;
    }
    int p  = idx - 1;
    int ph = p >> 6, pw = p & 63;

    __shared__ float xs[12];
    if (c < 12) {
        int ch = c >> 2, r = (c >> 1) & 1, q = c & 1;
        xs[c] = x[(((size_t)b * 3 + ch) * 128 + (ph * 2 + r)) * 128 + (pw * 2 + q)];
    }
    __syncthreads();

    float acc = bp[c];
    #pragma unroll
    for (int t = 0; t < 12; ++t) acc += xs[t] * Wp[c * 12 + t];

    int part = c >> 6, cc = c & 63;
    double omega = exp((double)cc * -0.14391156831212787);
    double posv  = (part < 2) ? (double)pw : (double)ph;
    double a     = posv * omega;
    double e     = ((part & 1) == 0) ? sin(a) : cos(a);
    float v = acc + (float)e;
    out[(size_t)row * 256 + c] = v;
    outb[(size_t)row * 256 + c] = f2b(v);
}

// ---------------------------------------------------------------------------
// bf16 MFMA GEMM: C[M,N] = act(A[M,K] @ Bt[N,K]^T + bias) (+Rsd)
// block 256 thr = 4 waves, tile (64*MT) x 64, K-step 32, 16x16x32 MFMA.
// M % (64*MT) == 0, N % 64 == 0, K % 32 == 0.
// ---------------------------------------------------------------------------
template<int MT, int ACT, bool RES, bool FOUT, bool BOUT>
__global__ __launch_bounds__(256) void gemm_mfma(
    const unsigned short* __restrict__ A, const unsigned short* __restrict__ Bt,
    const float* __restrict__ bias, const float* __restrict__ Rsd,
    float* __restrict__ C, unsigned short* __restrict__ Cb,
    int M, int N, int K)
{
    constexpr int BM = 64 * MT;
    __shared__ __align__(16) unsigned short As[BM * 40];
    __shared__ __align__(16) unsigned short Bs[64 * 40];
    int tid = threadIdx.x;
    int w = tid >> 6, lane = tid & 63;
    int l15 = lane & 15, q = lane >> 4;
    int row0 = blockIdx.y * BM, col0 = blockIdx.x * 64;

    f32x4 acc[MT][4];
    #pragma unroll
    for (int mt = 0; mt < MT; ++mt)
        #pragma unroll
        for (int nt = 0; nt < 4; ++nt)
            acc[mt][nt] = (f32x4){0.f, 0.f, 0.f, 0.f};

    for (int kb = 0; kb < K; kb += 32) {
        #pragma unroll
        for (int t = 0; t < MT; ++t) {
            int sid = tid + t * 256;
            int r = sid >> 2, s = sid & 3;
            *(uint4*)&As[r * 40 + s * 8] =
                *(const uint4*)(A + (size_t)(row0 + r) * K + kb + s * 8);
        }
        {
            int r = tid >> 2, s = tid & 3;
            *(uint4*)&Bs[r * 40 + s * 8] =
                *(const uint4*)(Bt + (size_t)(col0 + r) * K + kb + s * 8);
        }
        __syncthreads();

        short8 af[MT];
        #pragma unroll
        for (int mt = 0; mt < MT; ++mt)
            af[mt] = *(const short8*)&As[(w * 16 * MT + mt * 16 + l15) * 40 + q * 8];
        #pragma unroll
        for (int nt = 0; nt < 4; ++nt) {
            short8 bf = *(const short8*)&Bs[(nt * 16 + l15) * 40 + q * 8];
            #pragma unroll
            for (int mt = 0; mt < MT; ++mt)
                acc[mt][nt] = __builtin_amdgcn_mfma_f32_16x16x32_bf16(
                    af[mt], bf, acc[mt][nt], 0, 0, 0);
        }
        __syncthreads();
    }

    #pragma unroll
    for (int mt = 0; mt < MT; ++mt) {
        #pragma unroll
        for (int nt = 0; nt < 4; ++nt) {
            #pragma unroll
            for (int reg = 0; reg < 4; ++reg) {
                int row = row0 + w * 16 * MT + mt * 16 + q * 4 + reg;
                int col = col0 + nt * 16 + l15;
                float v = acc[mt][nt][reg] + bias[col];
                if (ACT == ACT_GELU) v = gelu_erf(v);
                if (RES) v += Rsd[(size_t)row * N + col];
                if (FOUT) C[(size_t)row * N + col] = v;
                if (BOUT) Cb[(size_t)row * N + col] = f2b(v);
            }
        }
    }
}

// ---------------------------------------------------------------------------
// Fused channel attention: o2 = sigmoid(relu(xl@ca1+b1)@ca2+b2) * xl
// one block (256 thr) per row.
// ---------------------------------------------------------------------------
__global__ __launch_bounds__(256) void chanattn_kernel(
    const float* __restrict__ xl, const float* __restrict__ ca1w,
    const float* __restrict__ ca1b, const float* __restrict__ ca2w,
    const float* __restrict__ ca2b, float* __restrict__ o2)
{
    __shared__ float xs[256];
    __shared__ float sm16[16];
    size_t row = blockIdx.x;
    int tid = threadIdx.x;
    xs[tid] = xl[row * 256 + tid];
    __syncthreads();

    int h = tid >> 4, part = tid & 15;
    float p = 0.f;
    #pragma unroll
    for (int i = 0; i < 16; ++i)
        p += xs[part * 16 + i] * ca1w[(part * 16 + i) * 16 + h];
    p += __shfl_down(p, 8, 16);
    p += __shfl_down(p, 4, 16);
    p += __shfl_down(p, 2, 16);
    p += __shfl_down(p, 1, 16);
    if (part == 0) sm16[h] = fmaxf(p + ca1b[h], 0.0f);
    __syncthreads();

    float g = ca2b[tid];
    #pragma unroll
    for (int hh = 0; hh < 16; ++hh) g += sm16[hh] * ca2w[hh * 256 + tid];
    g = 1.0f / (1.0f + expf(-g));
    o2[row * 256 + tid] = g * xs[tid];
}

// ---------------------------------------------------------------------------
// mixed = sum_n softmax(node_w[:cnt]/0.01)[n] * feat_n   (fp32 + bf16 out)
// ---------------------------------------------------------------------------
__global__ __launch_bounds__(256) void mix_kernel(
    const float* p0, const float* p1, const float* p2, const float* p3,
    const float* p4, const float* p5, const float* p6, const float* p7,
    const float* __restrict__ node_w, int cnt,
    float* __restrict__ out, unsigned short* __restrict__ outb, int n)
{
    int i = blockIdx.x * 256 + threadIdx.x;
    if (i >= n) return;
    float w[8];
    float mx = -1e30f;
    for (int t = 0; t < cnt; ++t) { w[t] = node_w[t] * 100.0f; mx = fmaxf(mx, w[t]); }
    float s = 0.0f;
    for (int t = 0; t < cnt; ++t) { w[t] = expf(w[t] - mx); s += w[t]; }
    float inv = 1.0f / s;
    const float* ps[8] = {p0, p1, p2, p3, p4, p5, p6, p7};
    float v = 0.0f;
    for (int t = 0; t < cnt; ++t) v += w[t] * inv * ps[t][i];
    out[i] = v;
    outb[i] = f2b(v);
}

// ---------------------------------------------------------------------------
// Row LayerNorm -> bf16 output. One block per row.
// ---------------------------------------------------------------------------
__global__ __launch_bounds__(256) void ln_kernel(
    const float* __restrict__ in, unsigned short* __restrict__ outb,
    const float* __restrict__ g, const float* __restrict__ bb, int N)
{
    __shared__ float sm[4];
    size_t row = blockIdx.x;
    const float* xr = in + row * N;
    int lane = threadIdx.x & 63, wid = threadIdx.x >> 6;

    float s = 0.0f;
    for (int i = threadIdx.x; i < N; i += 256) s += xr[i];
    #pragma unroll
    for (int off = 32; off > 0; off >>= 1) s += __shfl_down(s, off, 64);
    if (lane == 0) sm[wid] = s;
    __syncthreads();
    float mu = (sm[0] + sm[1] + sm[2] + sm[3]) / N;
    __syncthreads();

    float s2 = 0.0f;
    for (int i = threadIdx.x; i < N; i += 256) { float d = xr[i] - mu; s2 += d * d; }
    #pragma unroll
    for (int off = 32; off > 0; off >>= 1) s2 += __shfl_down(s2, off, 64);
    if (lane == 0) sm[wid] = s2;
    __syncthreads();
    float var = (sm[0] + sm[1] + sm[2] + sm[3]) / N;
    float rstd = rsqrtf(var + 1e-5f);

    for (int i = threadIdx.x; i < N; i += 256)
        outb[row * N + i] = f2b((xr[i] - mu) * rstd * g[i] + bb[i]);
}

// ---------------------------------------------------------------------------
// Fused attention (fp32 flash), bf16 output for proj input.
// ---------------------------------------------------------------------------
__global__ __launch_bounds__(256) void attn_kernel(
    const float* __restrict__ qkv,
    const float* __restrict__ nqg, const float* __restrict__ nqb,
    const float* __restrict__ nkg, const float* __restrict__ nkb,
    unsigned short* __restrict__ outb)
{
    int qt = blockIdx.x, h = blockIdx.y, b = blockIdx.z;
    int tid = threadIdx.x;
    __shared__ float kv[256][36];

    int qrow = qt * 256 + tid;
    const float* qp = qkv + ((size_t)(b * 1024 + qrow)) * 768 + h * 16;

    float q[16];
    float mu = 0.0f;
    #pragma unroll
    for (int d = 0; d < 16; ++d) { q[d] = qp[d]; mu += q[d]; }
    mu *= (1.0f / 16.0f);
    float var = 0.0f;
    #pragma unroll
    for (int d = 0; d < 16; ++d) { float t = q[d] - mu; var += t * t; }
    var *= (1.0f / 16.0f);
    float rstd = rsqrtf(var + 1e-5f);
    #pragma unroll
    for (int d = 0; d < 16; ++d) q[d] = ((q[d] - mu) * rstd * nqg[d] + nqb[d]) * 0.25f;

    float mrun = -1e30f, l = 0.0f;
    float acc[16] = {};

    for (int chunk = 0; chunk < 4; ++chunk) {
        __syncthreads();
        int krow = chunk * 256 + tid;
        const float* kp = qkv + ((size_t)(b * 1024 + krow)) * 768 + 256 + h * 16;
        float kr[16];
        float kmu = 0.0f;
        #pragma unroll
        for (int d = 0; d < 16; ++d) { kr[d] = kp[d]; kmu += kr[d]; }
        kmu *= (1.0f / 16.0f);
        float kvar = 0.0f;
        #pragma unroll
        for (int d = 0; d < 16; ++d) { float t = kr[d] - kmu; kvar += t * t; }
        kvar *= (1.0f / 16.0f);
        float krstd = rsqrtf(kvar + 1e-5f);
        #pragma unroll
        for (int d = 0; d < 16; ++d) kv[tid][d] = (kr[d] - kmu) * krstd * nkg[d] + nkb[d];
        const float* vp = kp + 256;
        #pragma unroll
        for (int d = 0; d < 16; ++d) kv[tid][16 + d] = vp[d];
        __syncthreads();

        for (int kk = 0; kk < 256; ++kk) {
            float s = 0.0f;
            #pragma unroll
            for (int d = 0; d < 16; ++d) s += q[d] * kv[kk][d];
            float mnew = fmaxf(mrun, s);
            float corr = expf(mrun - mnew);
            float e    = expf(s - mnew);
            l = l * corr + e;
            #pragma unroll
            for (int d = 0; d < 16; ++d) acc[d] = acc[d] * corr + e * kv[kk][16 + d];
            mrun = mnew;
        }
    }

    float invl = 1.0f / l;
    unsigned short* op = outb + ((size_t)(b * 1024 + qrow)) * 256 + h * 16;
    #pragma unroll
    for (int d = 0; d < 16; ++d) op[d] = f2b(acc[d] * invl);
}

// ---------------------------------------------------------------------------
static void wt_launch(const float* in, unsigned short* out, int K, int N,
                      hipStream_t s)
{
    wtrans_kernel<<<dim3(K / 32, N / 32), dim3(32, 8), 0, s>>>(in, out, K, N);
}

extern "C" void kernel_launch(void* const* d_in, const int* in_sizes, int n_in,
                              void* d_out, int out_size, void* d_ws, size_t ws_size,
                              hipStream_t stream)
{
    const float* x          = (const float*)d_in[0];
    const int*   mask_index = (const int*)  d_in[1];
    const float* Wp         = (const float*)d_in[2];
    const float* bp         = (const float*)d_in[3];
    const float* cls        = (const float*)d_in[4];
    const float* qkv_w      = (const float*)d_in[5];
    const float* qkv_b      = (const float*)d_in[6];
    const float* proj_w     = (const float*)d_in[7];
    const float* proj_b     = (const float*)d_in[8];
    const float* nq_g       = (const float*)d_in[9];
    const float* nq_b       = (const float*)d_in[10];
    const float* nk_g       = (const float*)d_in[11];
    const float* nk_b       = (const float*)d_in[12];
    const float* conv_w     = (const float*)d_in[13];
    const float* conv_b     = (const float*)d_in[14];
    const float* ca1_w      = (const float*)d_in[15];
    const float* ca1_b      = (const float*)d_in[16];
    const float* ca2_w      = (const float*)d_in[17];
    const float* ca2_b      = (const float*)d_in[18];
    const float* mlp1_w     = (const float*)d_in[19];
    const float* mlp1_b     = (const float*)d_in[20];
    const float* mlp2_w     = (const float*)d_in[21];
    const float* mlp2_b     = (const float*)d_in[22];
    const float* node_w     = (const float*)d_in[23];
    const float* ln0_g      = (const float*)d_in[24];
    const float* ln0_b      = (const float*)d_in[25];
    const float* h1_w       = (const float*)d_in[26];
    const float* h1_b       = (const float*)d_in[27];
    const float* ln1_g      = (const float*)d_in[28];
    const float* ln1_b      = (const float*)d_in[29];
    const float* h2_w       = (const float*)d_in[30];
    const float* h2_b       = (const float*)d_in[31];
    const float* ln2_g      = (const float*)d_in[32];
    const float* ln2_b      = (const float*)d_in[33];
    const float* h3_w       = (const float*)d_in[34];
    const float* h3_b       = (const float*)d_in[35];
    const float* pr_w       = (const float*)d_in[36];
    const float* pr_b       = (const float*)d_in[37];
    float* out = (float*)d_out;

    // ---- workspace layout (bytes) ----
    char* base = (char*)d_ws;
    size_t off = 0;
    auto alloc = [&](size_t bytes) -> char* {
        char* p = base + off;
        off += (bytes + 255) & ~(size_t)255;
        return p;
    };
    const size_t RC = (size_t)RTOK * CDIM;            // 1M elements
    float* F[5];
    unsigned short* Fb[5];
    for (int i = 0; i < 5; ++i) F[i] = (float*)alloc(RC * 4);
    for (int i = 0; i < 5; ++i) Fb[i] = (unsigned short*)alloc(RC * 2);
    float* O1  = (float*)alloc(RC * 4);
    float* O2  = (float*)alloc(RC * 4);
    float* O4  = (float*)alloc(RC * 4);
    float* MIX = (float*)alloc(RC * 4);
    unsigned short* MIXb = (unsigned short*)alloc(RC * 2);
    unsigned short* AOb  = (unsigned short*)alloc(RC * 2);
    float* BIGF = (float*)alloc((size_t)RTOK * 2048 * 4);      // QKV (iters) / HA (head)
    unsigned short* MIDU = (unsigned short*)alloc((size_t)RTOK * 2048 * 2); // T4b / L1b
    unsigned short* L0b  = (unsigned short*)alloc(RC * 2);
    unsigned short* L2b  = (unsigned short*)alloc(RC * 2);
    unsigned short* H3b  = (unsigned short*)alloc((size_t)RTOK * 2048 * 2);
    // bf16 transposed weights
    unsigned short* convb = (unsigned short*)alloc((size_t)4 * 256 * 256 * 2);
    unsigned short* qkvb  = (unsigned short*)alloc((size_t)4 * 768 * 256 * 2);
    unsigned short* projb = (unsigned short*)alloc((size_t)4 * 256 * 256 * 2);
    unsigned short* mlp1b = (unsigned short*)alloc((size_t)4 * 1024 * 256 * 2);
    unsigned short* mlp2b = (unsigned short*)alloc((size_t)4 * 256 * 1024 * 2);
    unsigned short* h1b   = (unsigned short*)alloc((size_t)2048 * 256 * 2);
    unsigned short* h2b   = (unsigned short*)alloc((size_t)256 * 2048 * 2);
    unsigned short* h3b   = (unsigned short*)alloc((size_t)2048 * 256 * 2);
    unsigned short* prb   = (unsigned short*)alloc((size_t)512 * 2048 * 2);

    // ---- weight conversion (transpose to [N,K] bf16) ----
    for (int j = 0; j < 4; ++j) {
        wt_launch(conv_w + (size_t)j * 256 * 256,  convb + (size_t)j * 256 * 256,  256, 256,  stream);
        wt_launch(qkv_w  + (size_t)j * 256 * 768,  qkvb  + (size_t)j * 768 * 256,  256, 768,  stream);
        wt_launch(proj_w + (size_t)j * 256 * 256,  projb + (size_t)j * 256 * 256,  256, 256,  stream);
        wt_launch(mlp1_w + (size_t)j * 256 * 1024, mlp1b + (size_t)j * 1024 * 256, 256, 1024, stream);
        wt_launch(mlp2_w + (size_t)j * 1024 * 256, mlp2b + (size_t)j * 256 * 1024, 1024, 256, stream);
    }
    wt_launch(h1_w, h1b, 256, 2048,  stream);
    wt_launch(h2_w, h2b, 2048, 256,  stream);
    wt_launch(h3_w, h3b, 256, 2048,  stream);
    wt_launch(pr_w, prb, 2048, 512,  stream);

    // ---- embed ----
    embed_kernel<<<RTOK, 256, 0, stream>>>(x, mask_index, Wp, bp, cls, F[0], Fb[0]);

    // ---- 4 block iterations ----
    for (int j = 0; j < 4; ++j) {
        const float* xl = F[j];
        const unsigned short* xlb = Fb[j];
        // o1 = gelu(xl @ conv_w + b)
        gemm_mfma<1, ACT_GELU, false, true, false><<<dim3(4, 64), 256, 0, stream>>>(
            xlb, convb + (size_t)j * 256 * 256, conv_b + j * 256, nullptr,
            O1, nullptr, RTOK, 256, 256);
        // o2 = channel attention
        chanattn_kernel<<<RTOK, 256, 0, stream>>>(
            xl, ca1_w + (size_t)j * 256 * 16, ca1_b + j * 16,
            ca2_w + (size_t)j * 16 * 256, ca2_b + j * 256, O2);
        // o4 = gelu(xl@mlp1+b)@mlp2+b
        gemm_mfma<2, ACT_GELU, false, false, true><<<dim3(16, 32), 256, 0, stream>>>(
            xlb, mlp1b + (size_t)j * 1024 * 256, mlp1_b + j * 1024, nullptr,
            nullptr, MIDU, RTOK, 1024, 256);
        gemm_mfma<1, ACT_NONE, false, true, false><<<dim3(4, 64), 256, 0, stream>>>(
            MIDU, mlp2b + (size_t)j * 256 * 1024, mlp2_b + j * 256, nullptr,
            O4, nullptr, RTOK, 256, 1024);
        // mix
        const float* ps[8] = {nullptr, nullptr, nullptr, nullptr,
                              nullptr, nullptr, nullptr, nullptr};
        int cnt = 0;
        for (int t = 0; t <= j; ++t) ps[cnt++] = F[t];
        ps[cnt++] = O1; ps[cnt++] = O2; ps[cnt++] = F[j]; ps[cnt++] = O4;
        mix_kernel<<<(int)(RC / 256), 256, 0, stream>>>(
            ps[0], ps[1], ps[2], ps[3], ps[4], ps[5], ps[6], ps[7],
            node_w + j * 8, cnt, MIX, MIXb, (int)RC);
        // attention
        gemm_mfma<2, ACT_NONE, false, true, false><<<dim3(12, 32), 256, 0, stream>>>(
            MIXb, qkvb + (size_t)j * 768 * 256, qkv_b + j * 768, nullptr,
            BIGF, nullptr, RTOK, 768, 256);
        attn_kernel<<<dim3(4, NHEAD, BSZ), 256, 0, stream>>>(
            BIGF, nq_g + j * 16, nq_b + j * 16, nk_g + j * 16, nk_b + j * 16, AOb);
        // xo = AO @ proj + b + mixed
        gemm_mfma<1, ACT_NONE, true, true, true><<<dim3(4, 64), 256, 0, stream>>>(
            AOb, projb + (size_t)j * 256 * 256, proj_b + j * 256, MIX,
            F[j + 1], Fb[j + 1], RTOK, 256, 256);
    }

    // ---- predict head ----
    ln_kernel<<<RTOK, 256, 0, stream>>>(F[4], L0b, ln0_g, ln0_b, 256);
    gemm_mfma<2, ACT_NONE, false, true, false><<<dim3(32, 32), 256, 0, stream>>>(
        L0b, h1b, h1_b, nullptr, BIGF, nullptr, RTOK, 2048, 256);
    ln_kernel<<<RTOK, 256, 0, stream>>>(BIGF, MIDU, ln1_g, ln1_b, 2048);
    gemm_mfma<1, ACT_NONE, false, true, false><<<dim3(4, 64), 256, 0, stream>>>(
        MIDU, h2b, h2_b, nullptr, MIX, nullptr, RTOK, 256, 2048);
    ln_kernel<<<RTOK, 256, 0, stream>>>(MIX, L2b, ln2_g, ln2_b, 256);
    gemm_mfma<2, ACT_NONE, false, false, true><<<dim3(32, 32), 256, 0, stream>>>(
        L2b, h3b, h3_b, nullptr, nullptr, H3b, RTOK, 2048, 256);
    gemm_mfma<1, ACT_NONE, false, true, false><<<dim3(8, 64), 256, 0, stream>>>(
        H3b, prb, pr_b, nullptr, out, nullptr, RTOK, 512, 2048);
}

// Round 3
// 1288.919 us; speedup vs baseline: 2.8968x; 1.1232x over previous
//
#include <hip/hip_runtime.h>
#include <math.h>
#include <cstddef>

// ---- problem constants ----
#define RTOK 4096
#define CDIM 256
#define NHEAD 16
#define DHEAD 16
#define SEQ 1024
#define BSZ 4

#define ACT_NONE 0
#define ACT_GELU 1

typedef short short8 __attribute__((ext_vector_type(8)));
typedef float f32x4  __attribute__((ext_vector_type(4)));

__device__ __forceinline__ float gelu_erf(float x) {
    return 0.5f * x * (1.0f + erff(x * 0.70710678118654752f));
}
__device__ __forceinline__ unsigned short f2b(float f) {
    unsigned u = __float_as_uint(f);
    unsigned r = (u + 0x7FFFu + ((u >> 16) & 1u)) >> 16;
    return (unsigned short)r;
}

// ---------------------------------------------------------------------------
// Weight convert+transpose: in [K,N] fp32 -> out [N,K] bf16. 32x32 LDS tile.
// ---------------------------------------------------------------------------
__global__ __launch_bounds__(256) void wtrans_kernel(
    const float* __restrict__ in, unsigned short* __restrict__ out, int K, int N)
{
    __shared__ float t[32][33];
    int kb = blockIdx.x * 32, nb = blockIdx.y * 32;
    int tx = threadIdx.x, ty = threadIdx.y;   // 32 x 8
    #pragma unroll
    for (int r = 0; r < 4; ++r) {
        int kk = ty * 4 + r;
        t[kk][tx] = in[(size_t)(kb + kk) * N + nb + tx];
    }
    __syncthreads();
    #pragma unroll
    for (int r = 0; r < 4; ++r) {
        int nn = ty * 4 + r;
        out[(size_t)(nb + nn) * K + kb + tx] = f2b(t[tx][nn]);
    }
}

// ---------------------------------------------------------------------------
// Fused patch-embed + pos-embed + cls + mask-gather (fp32 + bf16 outputs).
// ---------------------------------------------------------------------------
__global__ __launch_bounds__(256) void embed_kernel(
    const float* __restrict__ x, const int* __restrict__ mask_index,
    const float* __restrict__ Wp, const float* __restrict__ bp,
    const float* __restrict__ cls,
    float* __restrict__ out, unsigned short* __restrict__ outb)
{
    int row = blockIdx.x;
    int b = row >> 10;
    int c = threadIdx.x;
    int idx = mask_index[row];
    if (idx == 0) {
        float v = cls[c];
        out[(size_t)row * 256 + c] = v;
        outb[(size_t)row * 256 + c] = f2b(v);
        return;
    }
    int p  = idx - 1;
    int ph = p >> 6, pw = p & 63;

    __shared__ float xs[12];
    if (c < 12) {
        int ch = c >> 2, r = (c >> 1) & 1, q = c & 1;
        xs[c] = x[(((size_t)b * 3 + ch) * 128 + (ph * 2 + r)) * 128 + (pw * 2 + q)];
    }
    __syncthreads();

    float acc = bp[c];
    #pragma unroll
    for (int t = 0; t < 12; ++t) acc += xs[t] * Wp[c * 12 + t];

    int part = c >> 6, cc = c & 63;
    double omega = exp((double)cc * -0.14391156831212787);
    double posv  = (part < 2) ? (double)pw : (double)ph;
    double a     = posv * omega;
    double e     = ((part & 1) == 0) ? sin(a) : cos(a);
    float v = acc + (float)e;
    out[(size_t)row * 256 + c] = v;
    outb[(size_t)row * 256 + c] = f2b(v);
}

// ---------------------------------------------------------------------------
// bf16 MFMA GEMM: C[M,N] = act(A[M,K] @ Bt[N,K]^T + bias) (+Rsd)
// ---------------------------------------------------------------------------
template<int MT, int ACT, bool RES, bool FOUT, bool BOUT>
__global__ __launch_bounds__(256) void gemm_mfma(
    const unsigned short* __restrict__ A, const unsigned short* __restrict__ Bt,
    const float* __restrict__ bias, const float* __restrict__ Rsd,
    float* __restrict__ C, unsigned short* __restrict__ Cb,
    int M, int N, int K)
{
    constexpr int BM = 64 * MT;
    __shared__ __align__(16) unsigned short As[BM * 40];
    __shared__ __align__(16) unsigned short Bs[64 * 40];
    int tid = threadIdx.x;
    int w = tid >> 6, lane = tid & 63;
    int l15 = lane & 15, q = lane >> 4;
    int row0 = blockIdx.y * BM, col0 = blockIdx.x * 64;

    f32x4 acc[MT][4];
    #pragma unroll
    for (int mt = 0; mt < MT; ++mt)
        #pragma unroll
        for (int nt = 0; nt < 4; ++nt)
            acc[mt][nt] = (f32x4){0.f, 0.f, 0.f, 0.f};

    for (int kb = 0; kb < K; kb += 32) {
        #pragma unroll
        for (int t = 0; t < MT; ++t) {
            int sid = tid + t * 256;
            int r = sid >> 2, s = sid & 3;
            *(uint4*)&As[r * 40 + s * 8] =
                *(const uint4*)(A + (size_t)(row0 + r) * K + kb + s * 8);
        }
        {
            int r = tid >> 2, s = tid & 3;
            *(uint4*)&Bs[r * 40 + s * 8] =
                *(const uint4*)(Bt + (size_t)(col0 + r) * K + kb + s * 8);
        }
        __syncthreads();

        short8 af[MT];
        #pragma unroll
        for (int mt = 0; mt < MT; ++mt)
            af[mt] = *(const short8*)&As[(w * 16 * MT + mt * 16 + l15) * 40 + q * 8];
        #pragma unroll
        for (int nt = 0; nt < 4; ++nt) {
            short8 bf = *(const short8*)&Bs[(nt * 16 + l15) * 40 + q * 8];
            #pragma unroll
            for (int mt = 0; mt < MT; ++mt)
                acc[mt][nt] = __builtin_amdgcn_mfma_f32_16x16x32_bf16(
                    af[mt], bf, acc[mt][nt], 0, 0, 0);
        }
        __syncthreads();
    }

    #pragma unroll
    for (int mt = 0; mt < MT; ++mt) {
        #pragma unroll
        for (int nt = 0; nt < 4; ++nt) {
            #pragma unroll
            for (int reg = 0; reg < 4; ++reg) {
                int row = row0 + w * 16 * MT + mt * 16 + q * 4 + reg;
                int col = col0 + nt * 16 + l15;
                float v = acc[mt][nt][reg] + bias[col];
                if (ACT == ACT_GELU) v = gelu_erf(v);
                if (RES) v += Rsd[(size_t)row * N + col];
                if (FOUT) C[(size_t)row * N + col] = v;
                if (BOUT) Cb[(size_t)row * N + col] = f2b(v);
            }
        }
    }
}

// ---------------------------------------------------------------------------
// Fused channel attention: o2 = sigmoid(relu(xl@ca1+b1)@ca2+b2) * xl
// ---------------------------------------------------------------------------
__global__ __launch_bounds__(256) void chanattn_kernel(
    const float* __restrict__ xl, const float* __restrict__ ca1w,
    const float* __restrict__ ca1b, const float* __restrict__ ca2w,
    const float* __restrict__ ca2b, float* __restrict__ o2)
{
    __shared__ float xs[256];
    __shared__ float sm16[16];
    size_t row = blockIdx.x;
    int tid = threadIdx.x;
    xs[tid] = xl[row * 256 + tid];
    __syncthreads();

    int h = tid >> 4, part = tid & 15;
    float p = 0.f;
    #pragma unroll
    for (int i = 0; i < 16; ++i)
        p += xs[part * 16 + i] * ca1w[(part * 16 + i) * 16 + h];
    p += __shfl_down(p, 8, 16);
    p += __shfl_down(p, 4, 16);
    p += __shfl_down(p, 2, 16);
    p += __shfl_down(p, 1, 16);
    if (part == 0) sm16[h] = fmaxf(p + ca1b[h], 0.0f);
    __syncthreads();

    float g = ca2b[tid];
    #pragma unroll
    for (int hh = 0; hh < 16; ++hh) g += sm16[hh] * ca2w[hh * 256 + tid];
    g = 1.0f / (1.0f + expf(-g));
    o2[row * 256 + tid] = g * xs[tid];
}

// ---------------------------------------------------------------------------
// mixed = sum_n softmax(node_w[:cnt]/0.01)[n] * feat_n   (fp32 + bf16 out)
// ---------------------------------------------------------------------------
__global__ __launch_bounds__(256) void mix_kernel(
    const float* p0, const float* p1, const float* p2, const float* p3,
    const float* p4, const float* p5, const float* p6, const float* p7,
    const float* __restrict__ node_w, int cnt,
    float* __restrict__ out, unsigned short* __restrict__ outb, int n)
{
    int i = blockIdx.x * 256 + threadIdx.x;
    if (i >= n) return;
    float w[8];
    float mx = -1e30f;
    for (int t = 0; t < cnt; ++t) { w[t] = node_w[t] * 100.0f; mx = fmaxf(mx, w[t]); }
    float s = 0.0f;
    for (int t = 0; t < cnt; ++t) { w[t] = expf(w[t] - mx); s += w[t]; }
    float inv = 1.0f / s;
    const float* ps[8] = {p0, p1, p2, p3, p4, p5, p6, p7};
    float v = 0.0f;
    for (int t = 0; t < cnt; ++t) v += w[t] * inv * ps[t][i];
    out[i] = v;
    outb[i] = f2b(v);
}

// ---------------------------------------------------------------------------
// Row LayerNorm -> bf16 output. One block per row.
// ---------------------------------------------------------------------------
__global__ __launch_bounds__(256) void ln_kernel(
    const float* __restrict__ in, unsigned short* __restrict__ outb,
    const float* __restrict__ g, const float* __restrict__ bb, int N)
{
    __shared__ float sm[4];
    size_t row = blockIdx.x;
    const float* xr = in + row * N;
    int lane = threadIdx.x & 63, wid = threadIdx.x >> 6;

    float s = 0.0f;
    for (int i = threadIdx.x; i < N; i += 256) s += xr[i];
    #pragma unroll
    for (int off = 32; off > 0; off >>= 1) s += __shfl_down(s, off, 64);
    if (lane == 0) sm[wid] = s;
    __syncthreads();
    float mu = (sm[0] + sm[1] + sm[2] + sm[3]) / N;
    __syncthreads();

    float s2 = 0.0f;
    for (int i = threadIdx.x; i < N; i += 256) { float d = xr[i] - mu; s2 += d * d; }
    #pragma unroll
    for (int off = 32; off > 0; off >>= 1) s2 += __shfl_down(s2, off, 64);
    if (lane == 0) sm[wid] = s2;
    __syncthreads();
    float var = (sm[0] + sm[1] + sm[2] + sm[3]) / N;
    float rstd = rsqrtf(var + 1e-5f);

    for (int i = threadIdx.x; i < N; i += 256)
        outb[row * N + i] = f2b((xr[i] - mu) * rstd * g[i] + bb[i]);
}

// ---------------------------------------------------------------------------
// Key-split flash attention, stage 1.
// grid (qt=4, h=16, z = b*4+ks), 256 thr = 1 query each, 256 keys per split.
// Chunked rescale: 16-key chunks, one acc-rescale per chunk.
// Writes partial (acc[16], m, l) per (ks, b, h, q).
// ---------------------------------------------------------------------------
__global__ __launch_bounds__(256) void attn_kernel(
    const float* __restrict__ qkv,
    const float* __restrict__ nqg, const float* __restrict__ nqb,
    const float* __restrict__ nkg, const float* __restrict__ nkb,
    float* __restrict__ Pacc, float* __restrict__ Pml)
{
    int qt = blockIdx.x, h = blockIdx.y;
    int b = blockIdx.z >> 2, ks = blockIdx.z & 3;
    int tid = threadIdx.x;
    __shared__ float kv[256][33];   // [key][0:16 k_ln | 16:32 v | pad]

    int qrow = qt * 256 + tid;
    const float* qp = qkv + ((size_t)(b * 1024 + qrow)) * 768 + h * 16;

    // q load (vectorized) + LN + fold 1/sqrt(DH)
    float q[16];
    #pragma unroll
    for (int d4 = 0; d4 < 4; ++d4) {
        f32x4 t = *(const f32x4*)(qp + d4 * 4);
        q[d4 * 4 + 0] = t[0]; q[d4 * 4 + 1] = t[1];
        q[d4 * 4 + 2] = t[2]; q[d4 * 4 + 3] = t[3];
    }
    float mu = 0.0f;
    #pragma unroll
    for (int d = 0; d < 16; ++d) mu += q[d];
    mu *= (1.0f / 16.0f);
    float var = 0.0f;
    #pragma unroll
    for (int d = 0; d < 16; ++d) { float t = q[d] - mu; var += t * t; }
    var *= (1.0f / 16.0f);
    float rstd = rsqrtf(var + 1e-5f);
    #pragma unroll
    for (int d = 0; d < 16; ++d) q[d] = ((q[d] - mu) * rstd * nqg[d] + nqb[d]) * 0.25f;

    // stage this split's 256 keys (LN'd) + values into LDS
    int krow = ks * 256 + tid;
    const float* kp = qkv + ((size_t)(b * 1024 + krow)) * 768 + 256 + h * 16;
    float kr[16];
    #pragma unroll
    for (int d4 = 0; d4 < 4; ++d4) {
        f32x4 t = *(const f32x4*)(kp + d4 * 4);
        kr[d4 * 4 + 0] = t[0]; kr[d4 * 4 + 1] = t[1];
        kr[d4 * 4 + 2] = t[2]; kr[d4 * 4 + 3] = t[3];
    }
    float kmu = 0.0f;
    #pragma unroll
    for (int d = 0; d < 16; ++d) kmu += kr[d];
    kmu *= (1.0f / 16.0f);
    float kvar = 0.0f;
    #pragma unroll
    for (int d = 0; d < 16; ++d) { float t = kr[d] - kmu; kvar += t * t; }
    kvar *= (1.0f / 16.0f);
    float krstd = rsqrtf(kvar + 1e-5f);
    #pragma unroll
    for (int d = 0; d < 16; ++d) kv[tid][d] = (kr[d] - kmu) * krstd * nkg[d] + nkb[d];
    const float* vp = kp + 256;
    #pragma unroll
    for (int d4 = 0; d4 < 4; ++d4) {
        f32x4 t = *(const f32x4*)(vp + d4 * 4);
        kv[tid][16 + d4 * 4 + 0] = t[0]; kv[tid][16 + d4 * 4 + 1] = t[1];
        kv[tid][16 + d4 * 4 + 2] = t[2]; kv[tid][16 + d4 * 4 + 3] = t[3];
    }
    __syncthreads();

    float mrun = -1e30f, l = 0.0f;
    float acc[16] = {};

    for (int c = 0; c < 16; ++c) {          // 16 chunks x 16 keys
        float sc[16];
        float cmax = -1e30f;
        #pragma unroll
        for (int kk = 0; kk < 16; ++kk) {
            const float* kp2 = &kv[c * 16 + kk][0];
            float s = 0.0f;
            #pragma unroll
            for (int d = 0; d < 16; ++d) s += q[d] * kp2[d];
            sc[kk] = s;
            cmax = fmaxf(cmax, s);
        }
        float mnew = fmaxf(mrun, cmax);
        float corr = expf(mrun - mnew);
        l *= corr;
        #pragma unroll
        for (int d = 0; d < 16; ++d) acc[d] *= corr;
        #pragma unroll
        for (int kk = 0; kk < 16; ++kk) {
            float e = expf(sc[kk] - mnew);
            l += e;
            const float* vv = &kv[c * 16 + kk][16];
            #pragma unroll
            for (int d = 0; d < 16; ++d) acc[d] += e * vv[d];
        }
        mrun = mnew;
    }

    size_t u = ((size_t)b * 16 + h) * 1024 + qrow;
    float* pa = Pacc + ((size_t)ks * 65536 + u) * 16;
    #pragma unroll
    for (int d4 = 0; d4 < 4; ++d4) {
        f32x4 t = { acc[d4 * 4 + 0], acc[d4 * 4 + 1],
                    acc[d4 * 4 + 2], acc[d4 * 4 + 3] };
        *(f32x4*)(pa + d4 * 4) = t;
    }
    Pml[((size_t)ks * 65536 + u) * 2 + 0] = mrun;
    Pml[((size_t)ks * 65536 + u) * 2 + 1] = l;
}

// ---------------------------------------------------------------------------
// Key-split flash attention, stage 2: combine 4 partials, write bf16 out.
// ---------------------------------------------------------------------------
__global__ __launch_bounds__(256) void attn_combine(
    const float* __restrict__ Pacc, const float* __restrict__ Pml,
    unsigned short* __restrict__ outb)
{
    int u = blockIdx.x * 256 + threadIdx.x;   // (b,h,q) unit, 0..65535
    int b = u >> 14, h = (u >> 10) & 15, qrow = u & 1023;

    float ms[4], ls[4];
    float m = -1e30f;
    #pragma unroll
    for (int s = 0; s < 4; ++s) {
        ms[s] = Pml[((size_t)s * 65536 + u) * 2 + 0];
        ls[s] = Pml[((size_t)s * 65536 + u) * 2 + 1];
        m = fmaxf(m, ms[s]);
    }
    float l = 0.0f;
    float acc[16] = {};
    #pragma unroll
    for (int s = 0; s < 4; ++s) {
        float w = expf(ms[s] - m);
        l += ls[s] * w;
        const float* pa = Pacc + ((size_t)s * 65536 + u) * 16;
        #pragma unroll
        for (int d4 = 0; d4 < 4; ++d4) {
            f32x4 t = *(const f32x4*)(pa + d4 * 4);
            acc[d4 * 4 + 0] += w * t[0]; acc[d4 * 4 + 1] += w * t[1];
            acc[d4 * 4 + 2] += w * t[2]; acc[d4 * 4 + 3] += w * t[3];
        }
    }
    float invl = 1.0f / l;
    unsigned short* op = outb + ((size_t)(b * 1024 + qrow)) * 256 + h * 16;
    #pragma unroll
    for (int d = 0; d < 16; ++d) op[d] = f2b(acc[d] * invl);
}

// ---------------------------------------------------------------------------
static void wt_launch(const float* in, unsigned short* out, int K, int N,
                      hipStream_t s)
{
    wtrans_kernel<<<dim3(K / 32, N / 32), dim3(32, 8), 0, s>>>(in, out, K, N);
}

extern "C" void kernel_launch(void* const* d_in, const int* in_sizes, int n_in,
                              void* d_out, int out_size, void* d_ws, size_t ws_size,
                              hipStream_t stream)
{
    const float* x          = (const float*)d_in[0];
    const int*   mask_index = (const int*)  d_in[1];
    const float* Wp         = (const float*)d_in[2];
    const float* bp         = (const float*)d_in[3];
    const float* cls        = (const float*)d_in[4];
    const float* qkv_w      = (const float*)d_in[5];
    const float* qkv_b      = (const float*)d_in[6];
    const float* proj_w     = (const float*)d_in[7];
    const float* proj_b     = (const float*)d_in[8];
    const float* nq_g       = (const float*)d_in[9];
    const float* nq_b       = (const float*)d_in[10];
    const float* nk_g       = (const float*)d_in[11];
    const float* nk_b       = (const float*)d_in[12];
    const float* conv_w     = (const float*)d_in[13];
    const float* conv_b     = (const float*)d_in[14];
    const float* ca1_w      = (const float*)d_in[15];
    const float* ca1_b      = (const float*)d_in[16];
    const float* ca2_w      = (const float*)d_in[17];
    const float* ca2_b      = (const float*)d_in[18];
    const float* mlp1_w     = (const float*)d_in[19];
    const float* mlp1_b     = (const float*)d_in[20];
    const float* mlp2_w     = (const float*)d_in[21];
    const float* mlp2_b     = (const float*)d_in[22];
    const float* node_w     = (const float*)d_in[23];
    const float* ln0_g      = (const float*)d_in[24];
    const float* ln0_b      = (const float*)d_in[25];
    const float* h1_w       = (const float*)d_in[26];
    const float* h1_b       = (const float*)d_in[27];
    const float* ln1_g      = (const float*)d_in[28];
    const float* ln1_b      = (const float*)d_in[29];
    const float* h2_w       = (const float*)d_in[30];
    const float* h2_b       = (const float*)d_in[31];
    const float* ln2_g      = (const float*)d_in[32];
    const float* ln2_b      = (const float*)d_in[33];
    const float* h3_w       = (const float*)d_in[34];
    const float* h3_b       = (const float*)d_in[35];
    const float* pr_w       = (const float*)d_in[36];
    const float* pr_b       = (const float*)d_in[37];
    float* out = (float*)d_out;

    // ---- workspace layout ----
    char* base = (char*)d_ws;
    size_t off = 0;
    auto alloc = [&](size_t bytes) -> char* {
        char* p = base + off;
        off += (bytes + 255) & ~(size_t)255;
        return p;
    };
    const size_t RC = (size_t)RTOK * CDIM;
    float* F[5];
    unsigned short* Fb[5];
    for (int i = 0; i < 5; ++i) F[i] = (float*)alloc(RC * 4);
    for (int i = 0; i < 5; ++i) Fb[i] = (unsigned short*)alloc(RC * 2);
    float* O1  = (float*)alloc(RC * 4);
    float* O2  = (float*)alloc(RC * 4);
    float* O4  = (float*)alloc(RC * 4);
    float* MIX = (float*)alloc(RC * 4);
    unsigned short* MIXb = (unsigned short*)alloc(RC * 2);
    unsigned short* AOb  = (unsigned short*)alloc(RC * 2);
    float* BIGF = (float*)alloc((size_t)RTOK * 2048 * 4);
    unsigned short* MIDU = (unsigned short*)alloc((size_t)RTOK * 2048 * 2);
    unsigned short* L0b  = (unsigned short*)alloc(RC * 2);
    unsigned short* L2b  = (unsigned short*)alloc(RC * 2);
    unsigned short* H3b  = (unsigned short*)alloc((size_t)RTOK * 2048 * 2);
    float* Pacc = (float*)alloc((size_t)4 * 65536 * 16 * 4);   // 16.8 MB
    float* Pml  = (float*)alloc((size_t)4 * 65536 * 2 * 4);    // 2.1 MB
    // bf16 transposed weights
    unsigned short* convb = (unsigned short*)alloc((size_t)4 * 256 * 256 * 2);
    unsigned short* qkvb  = (unsigned short*)alloc((size_t)4 * 768 * 256 * 2);
    unsigned short* projb = (unsigned short*)alloc((size_t)4 * 256 * 256 * 2);
    unsigned short* mlp1b = (unsigned short*)alloc((size_t)4 * 1024 * 256 * 2);
    unsigned short* mlp2b = (unsigned short*)alloc((size_t)4 * 256 * 1024 * 2);
    unsigned short* h1b   = (unsigned short*)alloc((size_t)2048 * 256 * 2);
    unsigned short* h2b   = (unsigned short*)alloc((size_t)256 * 2048 * 2);
    unsigned short* h3b   = (unsigned short*)alloc((size_t)2048 * 256 * 2);
    unsigned short* prb   = (unsigned short*)alloc((size_t)512 * 2048 * 2);

    // ---- weight conversion ----
    for (int j = 0; j < 4; ++j) {
        wt_launch(conv_w + (size_t)j * 256 * 256,  convb + (size_t)j * 256 * 256,  256, 256,  stream);
        wt_launch(qkv_w  + (size_t)j * 256 * 768,  qkvb  + (size_t)j * 768 * 256,  256, 768,  stream);
        wt_launch(proj_w + (size_t)j * 256 * 256,  projb + (size_t)j * 256 * 256,  256, 256,  stream);
        wt_launch(mlp1_w + (size_t)j * 256 * 1024, mlp1b + (size_t)j * 1024 * 256, 256, 1024, stream);
        wt_launch(mlp2_w + (size_t)j * 1024 * 256, mlp2b + (size_t)j * 256 * 1024, 1024, 256, stream);
    }
    wt_launch(h1_w, h1b, 256, 2048,  stream);
    wt_launch(h2_w, h2b, 2048, 256,  stream);
    wt_launch(h3_w, h3b, 256, 2048,  stream);
    wt_launch(pr_w, prb, 2048, 512,  stream);

    // ---- embed ----
    embed_kernel<<<RTOK, 256, 0, stream>>>(x, mask_index, Wp, bp, cls, F[0], Fb[0]);

    // ---- 4 block iterations ----
    for (int j = 0; j < 4; ++j) {
        const float* xl = F[j];
        const unsigned short* xlb = Fb[j];
        gemm_mfma<1, ACT_GELU, false, true, false><<<dim3(4, 64), 256, 0, stream>>>(
            xlb, convb + (size_t)j * 256 * 256, conv_b + j * 256, nullptr,
            O1, nullptr, RTOK, 256, 256);
        chanattn_kernel<<<RTOK, 256, 0, stream>>>(
            xl, ca1_w + (size_t)j * 256 * 16, ca1_b + j * 16,
            ca2_w + (size_t)j * 16 * 256, ca2_b + j * 256, O2);
        gemm_mfma<2, ACT_GELU, false, false, true><<<dim3(16, 32), 256, 0, stream>>>(
            xlb, mlp1b + (size_t)j * 1024 * 256, mlp1_b + j * 1024, nullptr,
            nullptr, MIDU, RTOK, 1024, 256);
        gemm_mfma<1, ACT_NONE, false, true, false><<<dim3(4, 64), 256, 0, stream>>>(
            MIDU, mlp2b + (size_t)j * 256 * 1024, mlp2_b + j * 256, nullptr,
            O4, nullptr, RTOK, 256, 1024);
        const float* ps[8] = {nullptr, nullptr, nullptr, nullptr,
                              nullptr, nullptr, nullptr, nullptr};
        int cnt = 0;
        for (int t = 0; t <= j; ++t) ps[cnt++] = F[t];
        ps[cnt++] = O1; ps[cnt++] = O2; ps[cnt++] = F[j]; ps[cnt++] = O4;
        mix_kernel<<<(int)(RC / 256), 256, 0, stream>>>(
            ps[0], ps[1], ps[2], ps[3], ps[4], ps[5], ps[6], ps[7],
            node_w + j * 8, cnt, MIX, MIXb, (int)RC);
        gemm_mfma<2, ACT_NONE, false, true, false><<<dim3(12, 32), 256, 0, stream>>>(
            MIXb, qkvb + (size_t)j * 768 * 256, qkv_b + j * 768, nullptr,
            BIGF, nullptr, RTOK, 768, 256);
        attn_kernel<<<dim3(4, NHEAD, BSZ * 4), 256, 0, stream>>>(
            BIGF, nq_g + j * 16, nq_b + j * 16, nk_g + j * 16, nk_b + j * 16,
            Pacc, Pml);
        attn_combine<<<256, 256, 0, stream>>>(Pacc, Pml, AOb);
        gemm_mfma<1, ACT_NONE, true, true, true><<<dim3(4, 64), 256, 0, stream>>>(
            AOb, projb + (size_t)j * 256 * 256, proj_b + j * 256, MIX,
            F[j + 1], Fb[j + 1], RTOK, 256, 256);
    }

    // ---- predict head ----
    ln_kernel<<<RTOK, 256, 0, stream>>>(F[4], L0b, ln0_g, ln0_b, 256);
    gemm_mfma<2, ACT_NONE, false, true, false><<<dim3(32, 32), 256, 0, stream>>>(
        L0b, h1b, h1_b, nullptr, BIGF, nullptr, RTOK, 2048, 256);
    ln_kernel<<<RTOK, 256, 0, stream>>>(BIGF, MIDU, ln1_g, ln1_b, 2048);
    gemm_mfma<1, ACT_NONE, false, true, false><<<dim3(4, 64), 256, 0, stream>>>(
        MIDU, h2b, h2_b, nullptr, MIX, nullptr, RTOK, 256, 2048);
    ln_kernel<<<RTOK, 256, 0, stream>>>(MIX, L2b, ln2_g, ln2_b, 256);
    gemm_mfma<2, ACT_NONE, false, false, true><<<dim3(32, 32), 256, 0, stream>>>(
        L2b, h3b, h3_b, nullptr, nullptr, H3b, RTOK, 2048, 256);
    gemm_mfma<1, ACT_NONE, false, true, false><<<dim3(8, 64), 256, 0, stream>>>(
        H3b, prb, pr_b, nullptr, out, nullptr, RTOK, 512, 2048);
}

// Round 4
// 1125.254 us; speedup vs baseline: 3.3182x; 1.1454x over previous
//
#include <hip/hip_runtime.h>
#include <math.h>
#include <cstddef>

// ---- problem constants ----
#define RTOK 4096
#define CDIM 256
#define NHEAD 16
#define DHEAD 16
#define SEQ 1024
#define BSZ 4

#define ACT_NONE 0
#define ACT_GELU 1

typedef short short8 __attribute__((ext_vector_type(8)));
typedef float f32x4  __attribute__((ext_vector_type(4)));

__device__ __forceinline__ float gelu_erf(float x) {
    return 0.5f * x * (1.0f + erff(x * 0.70710678118654752f));
}
__device__ __forceinline__ unsigned short f2b(float f) {
    unsigned u = __float_as_uint(f);
    unsigned r = (u + 0x7FFFu + ((u >> 16) & 1u)) >> 16;
    return (unsigned short)r;
}

// ---------------------------------------------------------------------------
// Weight convert+transpose: in [K,N] fp32 -> out [N,K] bf16. 32x32 LDS tile.
// ---------------------------------------------------------------------------
__global__ __launch_bounds__(256) void wtrans_kernel(
    const float* __restrict__ in, unsigned short* __restrict__ out, int K, int N)
{
    __shared__ float t[32][33];
    int kb = blockIdx.x * 32, nb = blockIdx.y * 32;
    int tx = threadIdx.x, ty = threadIdx.y;   // 32 x 8
    #pragma unroll
    for (int r = 0; r < 4; ++r) {
        int kk = ty * 4 + r;
        t[kk][tx] = in[(size_t)(kb + kk) * N + nb + tx];
    }
    __syncthreads();
    #pragma unroll
    for (int r = 0; r < 4; ++r) {
        int nn = ty * 4 + r;
        out[(size_t)(nb + nn) * K + kb + tx] = f2b(t[tx][nn]);
    }
}

// ---------------------------------------------------------------------------
// Fused patch-embed + pos-embed + cls + mask-gather (fp32 + bf16 outputs).
// ---------------------------------------------------------------------------
__global__ __launch_bounds__(256) void embed_kernel(
    const float* __restrict__ x, const int* __restrict__ mask_index,
    const float* __restrict__ Wp, const float* __restrict__ bp,
    const float* __restrict__ cls,
    float* __restrict__ out, unsigned short* __restrict__ outb)
{
    int row = blockIdx.x;
    int b = row >> 10;
    int c = threadIdx.x;
    int idx = mask_index[row];
    if (idx == 0) {
        float v = cls[c];
        out[(size_t)row * 256 + c] = v;
        outb[(size_t)row * 256 + c] = f2b(v);
        return;
    }
    int p  = idx - 1;
    int ph = p >> 6, pw = p & 63;

    __shared__ float xs[12];
    if (c < 12) {
        int ch = c >> 2, r = (c >> 1) & 1, q = c & 1;
        xs[c] = x[(((size_t)b * 3 + ch) * 128 + (ph * 2 + r)) * 128 + (pw * 2 + q)];
    }
    __syncthreads();

    float acc = bp[c];
    #pragma unroll
    for (int t = 0; t < 12; ++t) acc += xs[t] * Wp[c * 12 + t];

    int part = c >> 6, cc = c & 63;
    double omega = exp((double)cc * -0.14391156831212787);
    double posv  = (part < 2) ? (double)pw : (double)ph;
    double a     = posv * omega;
    double e     = ((part & 1) == 0) ? sin(a) : cos(a);
    float v = acc + (float)e;
    out[(size_t)row * 256 + c] = v;
    outb[(size_t)row * 256 + c] = f2b(v);
}

// ---------------------------------------------------------------------------
// bf16 MFMA GEMM: C[M,N] = act(A[M,K] @ Bt[N,K]^T + bias) (+Rsd)
// ---------------------------------------------------------------------------
template<int MT, int ACT, bool RES, bool FOUT, bool BOUT>
__global__ __launch_bounds__(256) void gemm_mfma(
    const unsigned short* __restrict__ A, const unsigned short* __restrict__ Bt,
    const float* __restrict__ bias, const float* __restrict__ Rsd,
    float* __restrict__ C, unsigned short* __restrict__ Cb,
    int M, int N, int K)
{
    constexpr int BM = 64 * MT;
    __shared__ __align__(16) unsigned short As[BM * 40];
    __shared__ __align__(16) unsigned short Bs[64 * 40];
    int tid = threadIdx.x;
    int w = tid >> 6, lane = tid & 63;
    int l15 = lane & 15, q = lane >> 4;
    int row0 = blockIdx.y * BM, col0 = blockIdx.x * 64;

    f32x4 acc[MT][4];
    #pragma unroll
    for (int mt = 0; mt < MT; ++mt)
        #pragma unroll
        for (int nt = 0; nt < 4; ++nt)
            acc[mt][nt] = (f32x4){0.f, 0.f, 0.f, 0.f};

    for (int kb = 0; kb < K; kb += 32) {
        #pragma unroll
        for (int t = 0; t < MT; ++t) {
            int sid = tid + t * 256;
            int r = sid >> 2, s = sid & 3;
            *(uint4*)&As[r * 40 + s * 8] =
                *(const uint4*)(A + (size_t)(row0 + r) * K + kb + s * 8);
        }
        {
            int r = tid >> 2, s = tid & 3;
            *(uint4*)&Bs[r * 40 + s * 8] =
                *(const uint4*)(Bt + (size_t)(col0 + r) * K + kb + s * 8);
        }
        __syncthreads();

        short8 af[MT];
        #pragma unroll
        for (int mt = 0; mt < MT; ++mt)
            af[mt] = *(const short8*)&As[(w * 16 * MT + mt * 16 + l15) * 40 + q * 8];
        #pragma unroll
        for (int nt = 0; nt < 4; ++nt) {
            short8 bf = *(const short8*)&Bs[(nt * 16 + l15) * 40 + q * 8];
            #pragma unroll
            for (int mt = 0; mt < MT; ++mt)
                acc[mt][nt] = __builtin_amdgcn_mfma_f32_16x16x32_bf16(
                    af[mt], bf, acc[mt][nt], 0, 0, 0);
        }
        __syncthreads();
    }

    #pragma unroll
    for (int mt = 0; mt < MT; ++mt) {
        #pragma unroll
        for (int nt = 0; nt < 4; ++nt) {
            #pragma unroll
            for (int reg = 0; reg < 4; ++reg) {
                int row = row0 + w * 16 * MT + mt * 16 + q * 4 + reg;
                int col = col0 + nt * 16 + l15;
                float v = acc[mt][nt][reg] + bias[col];
                if (ACT == ACT_GELU) v = gelu_erf(v);
                if (RES) v += Rsd[(size_t)row * N + col];
                if (FOUT) C[(size_t)row * N + col] = v;
                if (BOUT) Cb[(size_t)row * N + col] = f2b(v);
            }
        }
    }
}

// ---------------------------------------------------------------------------
// Fused channel attention: o2 = sigmoid(relu(xl@ca1+b1)@ca2+b2) * xl
// ---------------------------------------------------------------------------
__global__ __launch_bounds__(256) void chanattn_kernel(
    const float* __restrict__ xl, const float* __restrict__ ca1w,
    const float* __restrict__ ca1b, const float* __restrict__ ca2w,
    const float* __restrict__ ca2b, float* __restrict__ o2)
{
    __shared__ float xs[256];
    __shared__ float sm16[16];
    size_t row = blockIdx.x;
    int tid = threadIdx.x;
    xs[tid] = xl[row * 256 + tid];
    __syncthreads();

    int h = tid >> 4, part = tid & 15;
    float p = 0.f;
    #pragma unroll
    for (int i = 0; i < 16; ++i)
        p += xs[part * 16 + i] * ca1w[(part * 16 + i) * 16 + h];
    p += __shfl_down(p, 8, 16);
    p += __shfl_down(p, 4, 16);
    p += __shfl_down(p, 2, 16);
    p += __shfl_down(p, 1, 16);
    if (part == 0) sm16[h] = fmaxf(p + ca1b[h], 0.0f);
    __syncthreads();

    float g = ca2b[tid];
    #pragma unroll
    for (int hh = 0; hh < 16; ++hh) g += sm16[hh] * ca2w[hh * 256 + tid];
    g = 1.0f / (1.0f + expf(-g));
    o2[row * 256 + tid] = g * xs[tid];
}

// ---------------------------------------------------------------------------
// mixed = sum_n softmax(node_w[:cnt]/0.01)[n] * feat_n   (fp32 + bf16 out)
// ---------------------------------------------------------------------------
__global__ __launch_bounds__(256) void mix_kernel(
    const float* p0, const float* p1, const float* p2, const float* p3,
    const float* p4, const float* p5, const float* p6, const float* p7,
    const float* __restrict__ node_w, int cnt,
    float* __restrict__ out, unsigned short* __restrict__ outb, int n)
{
    int i = blockIdx.x * 256 + threadIdx.x;
    if (i >= n) return;
    float w[8];
    float mx = -1e30f;
    for (int t = 0; t < cnt; ++t) { w[t] = node_w[t] * 100.0f; mx = fmaxf(mx, w[t]); }
    float s = 0.0f;
    for (int t = 0; t < cnt; ++t) { w[t] = expf(w[t] - mx); s += w[t]; }
    float inv = 1.0f / s;
    const float* ps[8] = {p0, p1, p2, p3, p4, p5, p6, p7};
    float v = 0.0f;
    for (int t = 0; t < cnt; ++t) v += w[t] * inv * ps[t][i];
    out[i] = v;
    outb[i] = f2b(v);
}

// ---------------------------------------------------------------------------
// Row LayerNorm -> bf16 output. One block per row.
// ---------------------------------------------------------------------------
__global__ __launch_bounds__(256) void ln_kernel(
    const float* __restrict__ in, unsigned short* __restrict__ outb,
    const float* __restrict__ g, const float* __restrict__ bb, int N)
{
    __shared__ float sm[4];
    size_t row = blockIdx.x;
    const float* xr = in + row * N;
    int lane = threadIdx.x & 63, wid = threadIdx.x >> 6;

    float s = 0.0f;
    for (int i = threadIdx.x; i < N; i += 256) s += xr[i];
    #pragma unroll
    for (int off = 32; off > 0; off >>= 1) s += __shfl_down(s, off, 64);
    if (lane == 0) sm[wid] = s;
    __syncthreads();
    float mu = (sm[0] + sm[1] + sm[2] + sm[3]) / N;
    __syncthreads();

    float s2 = 0.0f;
    for (int i = threadIdx.x; i < N; i += 256) { float d = xr[i] - mu; s2 += d * d; }
    #pragma unroll
    for (int off = 32; off > 0; off >>= 1) s2 += __shfl_down(s2, off, 64);
    if (lane == 0) sm[wid] = s2;
    __syncthreads();
    float var = (sm[0] + sm[1] + sm[2] + sm[3]) / N;
    float rstd = rsqrtf(var + 1e-5f);

    for (int i = threadIdx.x; i < N; i += 256)
        outb[row * N + i] = f2b((xr[i] - mu) * rstd * g[i] + bb[i]);
}

// ---------------------------------------------------------------------------
// Key-split flash attention, stage 1.  2 queries per thread.
// grid (qt=2, h=16, z = b*4+ks), 256 thr; 512 queries/block, 256 keys/split.
// LDS rows padded to 36 floats (144B) so k/v read as f32x4 (ds_read_b128).
// Scores carry log2e so exponentials are native exp2.
// ---------------------------------------------------------------------------
__global__ __launch_bounds__(256) void attn_kernel(
    const float* __restrict__ qkv,
    const float* __restrict__ nqg, const float* __restrict__ nqb,
    const float* __restrict__ nkg, const float* __restrict__ nkb,
    float* __restrict__ Pacc, float* __restrict__ Pml)
{
    int qt = blockIdx.x, h = blockIdx.y;
    int b = blockIdx.z >> 2, ks = blockIdx.z & 3;
    int tid = threadIdx.x;
    __shared__ __align__(16) float kv[256][36];  // [key][0:16 k_ln | 16:32 v | pad4]

    const float QSC = 0.25f * 1.44269504088896340736f;  // 1/sqrt(16) * log2(e)

    // ---- load + LN two queries ----
    int q0row = qt * 512 + tid;        // 0..1023
    int q1row = q0row + 256;
    float q0[16], q1[16];
    {
        const float* qp = qkv + ((size_t)(b * 1024 + q0row)) * 768 + h * 16;
        #pragma unroll
        for (int d4 = 0; d4 < 4; ++d4) {
            f32x4 t = *(const f32x4*)(qp + d4 * 4);
            q0[d4*4+0]=t[0]; q0[d4*4+1]=t[1]; q0[d4*4+2]=t[2]; q0[d4*4+3]=t[3];
        }
        const float* qp1 = qkv + ((size_t)(b * 1024 + q1row)) * 768 + h * 16;
        #pragma unroll
        for (int d4 = 0; d4 < 4; ++d4) {
            f32x4 t = *(const f32x4*)(qp1 + d4 * 4);
            q1[d4*4+0]=t[0]; q1[d4*4+1]=t[1]; q1[d4*4+2]=t[2]; q1[d4*4+3]=t[3];
        }
    }
    #pragma unroll
    for (int which = 0; which < 2; ++which) {
        float* q = which ? q1 : q0;
        float mu = 0.0f;
        #pragma unroll
        for (int d = 0; d < 16; ++d) mu += q[d];
        mu *= (1.0f / 16.0f);
        float var = 0.0f;
        #pragma unroll
        for (int d = 0; d < 16; ++d) { float t = q[d] - mu; var += t * t; }
        var *= (1.0f / 16.0f);
        float rstd = rsqrtf(var + 1e-5f);
        #pragma unroll
        for (int d = 0; d < 16; ++d)
            q[d] = ((q[d] - mu) * rstd * nqg[d] + nqb[d]) * QSC;
    }

    // ---- stage this split's 256 keys (LN'd) + values into LDS ----
    {
        int krow = ks * 256 + tid;
        const float* kp = qkv + ((size_t)(b * 1024 + krow)) * 768 + 256 + h * 16;
        float kr[16];
        #pragma unroll
        for (int d4 = 0; d4 < 4; ++d4) {
            f32x4 t = *(const f32x4*)(kp + d4 * 4);
            kr[d4*4+0]=t[0]; kr[d4*4+1]=t[1]; kr[d4*4+2]=t[2]; kr[d4*4+3]=t[3];
        }
        float kmu = 0.0f;
        #pragma unroll
        for (int d = 0; d < 16; ++d) kmu += kr[d];
        kmu *= (1.0f / 16.0f);
        float kvar = 0.0f;
        #pragma unroll
        for (int d = 0; d < 16; ++d) { float t = kr[d] - kmu; kvar += t * t; }
        kvar *= (1.0f / 16.0f);
        float krstd = rsqrtf(kvar + 1e-5f);
        #pragma unroll
        for (int d4 = 0; d4 < 4; ++d4) {
            f32x4 t;
            #pragma unroll
            for (int e = 0; e < 4; ++e)
                t[e] = (kr[d4*4+e] - kmu) * krstd * nkg[d4*4+e] + nkb[d4*4+e];
            *(f32x4*)&kv[tid][d4 * 4] = t;
        }
        const float* vp = kp + 256;
        #pragma unroll
        for (int d4 = 0; d4 < 4; ++d4)
            *(f32x4*)&kv[tid][16 + d4 * 4] = *(const f32x4*)(vp + d4 * 4);
    }
    __syncthreads();

    float m0 = -1e30f, l0 = 0.0f;
    float m1 = -1e30f, l1 = 0.0f;
    float acc0[16] = {}, acc1[16] = {};

    for (int c = 0; c < 16; ++c) {          // 16 chunks x 16 keys
        float sc0[16], sc1[16];
        float cm0 = -1e30f, cm1 = -1e30f;
        #pragma unroll
        for (int kk = 0; kk < 16; ++kk) {
            const float* kp2 = &kv[c * 16 + kk][0];
            f32x4 k0 = *(const f32x4*)(kp2);
            f32x4 k1 = *(const f32x4*)(kp2 + 4);
            f32x4 k2 = *(const f32x4*)(kp2 + 8);
            f32x4 k3 = *(const f32x4*)(kp2 + 12);
            float s0 = 0.f, s1 = 0.f;
            #pragma unroll
            for (int e = 0; e < 4; ++e) {
                s0 += q0[e] * k0[e] + q0[4+e] * k1[e] + q0[8+e] * k2[e] + q0[12+e] * k3[e];
                s1 += q1[e] * k0[e] + q1[4+e] * k1[e] + q1[8+e] * k2[e] + q1[12+e] * k3[e];
            }
            sc0[kk] = s0; cm0 = fmaxf(cm0, s0);
            sc1[kk] = s1; cm1 = fmaxf(cm1, s1);
        }
        float mn0 = fmaxf(m0, cm0);
        float mn1 = fmaxf(m1, cm1);
        float cor0 = exp2f(m0 - mn0);
        float cor1 = exp2f(m1 - mn1);
        l0 *= cor0; l1 *= cor1;
        #pragma unroll
        for (int d = 0; d < 16; ++d) { acc0[d] *= cor0; acc1[d] *= cor1; }
        #pragma unroll
        for (int kk = 0; kk < 16; ++kk) {
            const float* vv = &kv[c * 16 + kk][16];
            f32x4 v0 = *(const f32x4*)(vv);
            f32x4 v1 = *(const f32x4*)(vv + 4);
            f32x4 v2 = *(const f32x4*)(vv + 8);
            f32x4 v3 = *(const f32x4*)(vv + 12);
            float e0 = exp2f(sc0[kk] - mn0);
            float e1 = exp2f(sc1[kk] - mn1);
            l0 += e0; l1 += e1;
            #pragma unroll
            for (int e = 0; e < 4; ++e) {
                acc0[e]    += e0 * v0[e]; acc0[4+e]  += e0 * v1[e];
                acc0[8+e]  += e0 * v2[e]; acc0[12+e] += e0 * v3[e];
                acc1[e]    += e1 * v0[e]; acc1[4+e]  += e1 * v1[e];
                acc1[8+e]  += e1 * v2[e]; acc1[12+e] += e1 * v3[e];
            }
        }
        m0 = mn0; m1 = mn1;
    }

    size_t u0 = ((size_t)b * 16 + h) * 1024 + q0row;
    size_t u1 = ((size_t)b * 16 + h) * 1024 + q1row;
    float* pa0 = Pacc + ((size_t)ks * 65536 + u0) * 16;
    float* pa1 = Pacc + ((size_t)ks * 65536 + u1) * 16;
    #pragma unroll
    for (int d4 = 0; d4 < 4; ++d4) {
        f32x4 t0 = { acc0[d4*4+0], acc0[d4*4+1], acc0[d4*4+2], acc0[d4*4+3] };
        f32x4 t1 = { acc1[d4*4+0], acc1[d4*4+1], acc1[d4*4+2], acc1[d4*4+3] };
        *(f32x4*)(pa0 + d4 * 4) = t0;
        *(f32x4*)(pa1 + d4 * 4) = t1;
    }
    Pml[((size_t)ks * 65536 + u0) * 2 + 0] = m0;
    Pml[((size_t)ks * 65536 + u0) * 2 + 1] = l0;
    Pml[((size_t)ks * 65536 + u1) * 2 + 0] = m1;
    Pml[((size_t)ks * 65536 + u1) * 2 + 1] = l1;
}

// ---------------------------------------------------------------------------
// Key-split flash attention, stage 2: combine 4 partials (log2-domain m/l).
// ---------------------------------------------------------------------------
__global__ __launch_bounds__(256) void attn_combine(
    const float* __restrict__ Pacc, const float* __restrict__ Pml,
    unsigned short* __restrict__ outb)
{
    int u = blockIdx.x * 256 + threadIdx.x;   // (b,h,q) unit, 0..65535
    int b = u >> 14, h = (u >> 10) & 15, qrow = u & 1023;

    float ms[4], ls[4];
    float m = -1e30f;
    #pragma unroll
    for (int s = 0; s < 4; ++s) {
        ms[s] = Pml[((size_t)s * 65536 + u) * 2 + 0];
        ls[s] = Pml[((size_t)s * 65536 + u) * 2 + 1];
        m = fmaxf(m, ms[s]);
    }
    float l = 0.0f;
    float acc[16] = {};
    #pragma unroll
    for (int s = 0; s < 4; ++s) {
        float w = exp2f(ms[s] - m);
        l += ls[s] * w;
        const float* pa = Pacc + ((size_t)s * 65536 + u) * 16;
        #pragma unroll
        for (int d4 = 0; d4 < 4; ++d4) {
            f32x4 t = *(const f32x4*)(pa + d4 * 4);
            acc[d4 * 4 + 0] += w * t[0]; acc[d4 * 4 + 1] += w * t[1];
            acc[d4 * 4 + 2] += w * t[2]; acc[d4 * 4 + 3] += w * t[3];
        }
    }
    float invl = 1.0f / l;
    unsigned short* op = outb + ((size_t)(b * 1024 + qrow)) * 256 + h * 16;
    #pragma unroll
    for (int d = 0; d < 16; ++d) op[d] = f2b(acc[d] * invl);
}

// ---------------------------------------------------------------------------
static void wt_launch(const float* in, unsigned short* out, int K, int N,
                      hipStream_t s)
{
    wtrans_kernel<<<dim3(K / 32, N / 32), dim3(32, 8), 0, s>>>(in, out, K, N);
}

extern "C" void kernel_launch(void* const* d_in, const int* in_sizes, int n_in,
                              void* d_out, int out_size, void* d_ws, size_t ws_size,
                              hipStream_t stream)
{
    const float* x          = (const float*)d_in[0];
    const int*   mask_index = (const int*)  d_in[1];
    const float* Wp         = (const float*)d_in[2];
    const float* bp         = (const float*)d_in[3];
    const float* cls        = (const float*)d_in[4];
    const float* qkv_w      = (const float*)d_in[5];
    const float* qkv_b      = (const float*)d_in[6];
    const float* proj_w     = (const float*)d_in[7];
    const float* proj_b     = (const float*)d_in[8];
    const float* nq_g       = (const float*)d_in[9];
    const float* nq_b       = (const float*)d_in[10];
    const float* nk_g       = (const float*)d_in[11];
    const float* nk_b       = (const float*)d_in[12];
    const float* conv_w     = (const float*)d_in[13];
    const float* conv_b     = (const float*)d_in[14];
    const float* ca1_w      = (const float*)d_in[15];
    const float* ca1_b      = (const float*)d_in[16];
    const float* ca2_w      = (const float*)d_in[17];
    const float* ca2_b      = (const float*)d_in[18];
    const float* mlp1_w     = (const float*)d_in[19];
    const float* mlp1_b     = (const float*)d_in[20];
    const float* mlp2_w     = (const float*)d_in[21];
    const float* mlp2_b     = (const float*)d_in[22];
    const float* node_w     = (const float*)d_in[23];
    const float* ln0_g      = (const float*)d_in[24];
    const float* ln0_b      = (const float*)d_in[25];
    const float* h1_w       = (const float*)d_in[26];
    const float* h1_b       = (const float*)d_in[27];
    const float* ln1_g      = (const float*)d_in[28];
    const float* ln1_b      = (const float*)d_in[29];
    const float* h2_w       = (const float*)d_in[30];
    const float* h2_b       = (const float*)d_in[31];
    const float* ln2_g      = (const float*)d_in[32];
    const float* ln2_b      = (const float*)d_in[33];
    const float* h3_w       = (const float*)d_in[34];
    const float* h3_b       = (const float*)d_in[35];
    const float* pr_w       = (const float*)d_in[36];
    const float* pr_b       = (const float*)d_in[37];
    float* out = (float*)d_out;

    // ---- workspace layout ----
    char* base = (char*)d_ws;
    size_t off = 0;
    auto alloc = [&](size_t bytes) -> char* {
        char* p = base + off;
        off += (bytes + 255) & ~(size_t)255;
        return p;
    };
    const size_t RC = (size_t)RTOK * CDIM;
    float* F[5];
    unsigned short* Fb[5];
    for (int i = 0; i < 5; ++i) F[i] = (float*)alloc(RC * 4);
    for (int i = 0; i < 5; ++i) Fb[i] = (unsigned short*)alloc(RC * 2);
    float* O1  = (float*)alloc(RC * 4);
    float* O2  = (float*)alloc(RC * 4);
    float* O4  = (float*)alloc(RC * 4);
    float* MIX = (float*)alloc(RC * 4);
    unsigned short* MIXb = (unsigned short*)alloc(RC * 2);
    unsigned short* AOb  = (unsigned short*)alloc(RC * 2);
    float* BIGF = (float*)alloc((size_t)RTOK * 2048 * 4);
    unsigned short* MIDU = (unsigned short*)alloc((size_t)RTOK * 2048 * 2);
    unsigned short* L0b  = (unsigned short*)alloc(RC * 2);
    unsigned short* L2b  = (unsigned short*)alloc(RC * 2);
    unsigned short* H3b  = (unsigned short*)alloc((size_t)RTOK * 2048 * 2);
    float* Pacc = (float*)alloc((size_t)4 * 65536 * 16 * 4);   // 16.8 MB
    float* Pml  = (float*)alloc((size_t)4 * 65536 * 2 * 4);    // 2.1 MB
    // bf16 transposed weights
    unsigned short* convb = (unsigned short*)alloc((size_t)4 * 256 * 256 * 2);
    unsigned short* qkvb  = (unsigned short*)alloc((size_t)4 * 768 * 256 * 2);
    unsigned short* projb = (unsigned short*)alloc((size_t)4 * 256 * 256 * 2);
    unsigned short* mlp1b = (unsigned short*)alloc((size_t)4 * 1024 * 256 * 2);
    unsigned short* mlp2b = (unsigned short*)alloc((size_t)4 * 256 * 1024 * 2);
    unsigned short* h1b   = (unsigned short*)alloc((size_t)2048 * 256 * 2);
    unsigned short* h2b   = (unsigned short*)alloc((size_t)256 * 2048 * 2);
    unsigned short* h3b   = (unsigned short*)alloc((size_t)2048 * 256 * 2);
    unsigned short* prb   = (unsigned short*)alloc((size_t)512 * 2048 * 2);

    // ---- weight conversion ----
    for (int j = 0; j < 4; ++j) {
        wt_launch(conv_w + (size_t)j * 256 * 256,  convb + (size_t)j * 256 * 256,  256, 256,  stream);
        wt_launch(qkv_w  + (size_t)j * 256 * 768,  qkvb  + (size_t)j * 768 * 256,  256, 768,  stream);
        wt_launch(proj_w + (size_t)j * 256 * 256,  projb + (size_t)j * 256 * 256,  256, 256,  stream);
        wt_launch(mlp1_w + (size_t)j * 256 * 1024, mlp1b + (size_t)j * 1024 * 256, 256, 1024, stream);
        wt_launch(mlp2_w + (size_t)j * 1024 * 256, mlp2b + (size_t)j * 256 * 1024, 1024, 256, stream);
    }
    wt_launch(h1_w, h1b, 256, 2048,  stream);
    wt_launch(h2_w, h2b, 2048, 256,  stream);
    wt_launch(h3_w, h3b, 256, 2048,  stream);
    wt_launch(pr_w, prb, 2048, 512,  stream);

    // ---- embed ----
    embed_kernel<<<RTOK, 256, 0, stream>>>(x, mask_index, Wp, bp, cls, F[0], Fb[0]);

    // ---- 4 block iterations ----
    for (int j = 0; j < 4; ++j) {
        const float* xl = F[j];
        const unsigned short* xlb = Fb[j];
        gemm_mfma<1, ACT_GELU, false, true, false><<<dim3(4, 64), 256, 0, stream>>>(
            xlb, convb + (size_t)j * 256 * 256, conv_b + j * 256, nullptr,
            O1, nullptr, RTOK, 256, 256);
        chanattn_kernel<<<RTOK, 256, 0, stream>>>(
            xl, ca1_w + (size_t)j * 256 * 16, ca1_b + j * 16,
            ca2_w + (size_t)j * 16 * 256, ca2_b + j * 256, O2);
        gemm_mfma<2, ACT_GELU, false, false, true><<<dim3(16, 32), 256, 0, stream>>>(
            xlb, mlp1b + (size_t)j * 1024 * 256, mlp1_b + j * 1024, nullptr,
            nullptr, MIDU, RTOK, 1024, 256);
        gemm_mfma<1, ACT_NONE, false, true, false><<<dim3(4, 64), 256, 0, stream>>>(
            MIDU, mlp2b + (size_t)j * 256 * 1024, mlp2_b + j * 256, nullptr,
            O4, nullptr, RTOK, 256, 1024);
        const float* ps[8] = {nullptr, nullptr, nullptr, nullptr,
                              nullptr, nullptr, nullptr, nullptr};
        int cnt = 0;
        for (int t = 0; t <= j; ++t) ps[cnt++] = F[t];
        ps[cnt++] = O1; ps[cnt++] = O2; ps[cnt++] = F[j]; ps[cnt++] = O4;
        mix_kernel<<<(int)(RC / 256), 256, 0, stream>>>(
            ps[0], ps[1], ps[2], ps[3], ps[4], ps[5], ps[6], ps[7],
            node_w + j * 8, cnt, MIX, MIXb, (int)RC);
        gemm_mfma<2, ACT_NONE, false, true, false><<<dim3(12, 32), 256, 0, stream>>>(
            MIXb, qkvb + (size_t)j * 768 * 256, qkv_b + j * 768, nullptr,
            BIGF, nullptr, RTOK, 768, 256);
        attn_kernel<<<dim3(2, NHEAD, BSZ * 4), 256, 0, stream>>>(
            BIGF, nq_g + j * 16, nq_b + j * 16, nk_g + j * 16, nk_b + j * 16,
            Pacc, Pml);
        attn_combine<<<256, 256, 0, stream>>>(Pacc, Pml, AOb);
        gemm_mfma<1, ACT_NONE, true, true, true><<<dim3(4, 64), 256, 0, stream>>>(
            AOb, projb + (size_t)j * 256 * 256, proj_b + j * 256, MIX,
            F[j + 1], Fb[j + 1], RTOK, 256, 256);
    }

    // ---- predict head ----
    ln_kernel<<<RTOK, 256, 0, stream>>>(F[4], L0b, ln0_g, ln0_b, 256);
    gemm_mfma<2, ACT_NONE, false, true, false><<<dim3(32, 32), 256, 0, stream>>>(
        L0b, h1b, h1_b, nullptr, BIGF, nullptr, RTOK, 2048, 256);
    ln_kernel<<<RTOK, 256, 0, stream>>>(BIGF, MIDU, ln1_g, ln1_b, 2048);
    gemm_mfma<1, ACT_NONE, false, true, false><<<dim3(4, 64), 256, 0, stream>>>(
        MIDU, h2b, h2_b, nullptr, MIX, nullptr, RTOK, 256, 2048);
    ln_kernel<<<RTOK, 256, 0, stream>>>(MIX, L2b, ln2_g, ln2_b, 256);
    gemm_mfma<2, ACT_NONE, false, false, true><<<dim3(32, 32), 256, 0, stream>>>(
        L2b, h3b, h3_b, nullptr, nullptr, H3b, RTOK, 2048, 256);
    gemm_mfma<1, ACT_NONE, false, true, false><<<dim3(8, 64), 256, 0, stream>>>(
        H3b, prb, pr_b, nullptr, out, nullptr, RTOK, 512, 2048);
}

// Round 5
// 910.512 us; speedup vs baseline: 4.1008x; 1.2358x over previous
//
#include <hip/hip_runtime.h>
#include <math.h>
#include <cstddef>

// ---- problem constants ----
#define RTOK 4096
#define CDIM 256
#define NHEAD 16
#define DHEAD 16
#define SEQ 1024
#define BSZ 4

#define ACT_NONE 0
#define ACT_GELU 1

typedef short short8 __attribute__((ext_vector_type(8)));
typedef float f32x4  __attribute__((ext_vector_type(4)));
typedef _Float16 half8 __attribute__((ext_vector_type(8)));
typedef _Float16 half4 __attribute__((ext_vector_type(4)));

__device__ __forceinline__ float gelu_erf(float x) {
    return 0.5f * x * (1.0f + erff(x * 0.70710678118654752f));
}
__device__ __forceinline__ unsigned short f2b(float f) {
    unsigned u = __float_as_uint(f);
    unsigned r = (u + 0x7FFFu + ((u >> 16) & 1u)) >> 16;
    return (unsigned short)r;
}

// ---------------------------------------------------------------------------
// Weight convert+transpose: in [K,N] fp32 -> out [N,K] bf16. 32x32 LDS tile.
// ---------------------------------------------------------------------------
__global__ __launch_bounds__(256) void wtrans_kernel(
    const float* __restrict__ in, unsigned short* __restrict__ out, int K, int N)
{
    __shared__ float t[32][33];
    int kb = blockIdx.x * 32, nb = blockIdx.y * 32;
    int tx = threadIdx.x, ty = threadIdx.y;   // 32 x 8
    #pragma unroll
    for (int r = 0; r < 4; ++r) {
        int kk = ty * 4 + r;
        t[kk][tx] = in[(size_t)(kb + kk) * N + nb + tx];
    }
    __syncthreads();
    #pragma unroll
    for (int r = 0; r < 4; ++r) {
        int nn = ty * 4 + r;
        out[(size_t)(nb + nn) * K + kb + tx] = f2b(t[tx][nn]);
    }
}

// ---------------------------------------------------------------------------
// Fused patch-embed + pos-embed + cls + mask-gather (fp32 + bf16 outputs).
// ---------------------------------------------------------------------------
__global__ __launch_bounds__(256) void embed_kernel(
    const float* __restrict__ x, const int* __restrict__ mask_index,
    const float* __restrict__ Wp, const float* __restrict__ bp,
    const float* __restrict__ cls,
    float* __restrict__ out, unsigned short* __restrict__ outb)
{
    int row = blockIdx.x;
    int b = row >> 10;
    int c = threadIdx.x;
    int idx = mask_index[row];
    if (idx == 0) {
        float v = cls[c];
        out[(size_t)row * 256 + c] = v;
        outb[(size_t)row * 256 + c] = f2b(v);
        return;
    }
    int p  = idx - 1;
    int ph = p >> 6, pw = p & 63;

    __shared__ float xs[12];
    if (c < 12) {
        int ch = c >> 2, r = (c >> 1) & 1, q = c & 1;
        xs[c] = x[(((size_t)b * 3 + ch) * 128 + (ph * 2 + r)) * 128 + (pw * 2 + q)];
    }
    __syncthreads();

    float acc = bp[c];
    #pragma unroll
    for (int t = 0; t < 12; ++t) acc += xs[t] * Wp[c * 12 + t];

    int part = c >> 6, cc = c & 63;
    double omega = exp((double)cc * -0.14391156831212787);
    double posv  = (part < 2) ? (double)pw : (double)ph;
    double a     = posv * omega;
    double e     = ((part & 1) == 0) ? sin(a) : cos(a);
    float v = acc + (float)e;
    out[(size_t)row * 256 + c] = v;
    outb[(size_t)row * 256 + c] = f2b(v);
}

// ---------------------------------------------------------------------------
// bf16 MFMA GEMM: C[M,N] = act(A[M,K] @ Bt[N,K]^T + bias) (+Rsd)
// ---------------------------------------------------------------------------
template<int MT, int ACT, bool RES, bool FOUT, bool BOUT>
__global__ __launch_bounds__(256) void gemm_mfma(
    const unsigned short* __restrict__ A, const unsigned short* __restrict__ Bt,
    const float* __restrict__ bias, const float* __restrict__ Rsd,
    float* __restrict__ C, unsigned short* __restrict__ Cb,
    int M, int N, int K)
{
    constexpr int BM = 64 * MT;
    __shared__ __align__(16) unsigned short As[BM * 40];
    __shared__ __align__(16) unsigned short Bs[64 * 40];
    int tid = threadIdx.x;
    int w = tid >> 6, lane = tid & 63;
    int l15 = lane & 15, q = lane >> 4;
    int row0 = blockIdx.y * BM, col0 = blockIdx.x * 64;

    f32x4 acc[MT][4];
    #pragma unroll
    for (int mt = 0; mt < MT; ++mt)
        #pragma unroll
        for (int nt = 0; nt < 4; ++nt)
            acc[mt][nt] = (f32x4){0.f, 0.f, 0.f, 0.f};

    for (int kb = 0; kb < K; kb += 32) {
        #pragma unroll
        for (int t = 0; t < MT; ++t) {
            int sid = tid + t * 256;
            int r = sid >> 2, s = sid & 3;
            *(uint4*)&As[r * 40 + s * 8] =
                *(const uint4*)(A + (size_t)(row0 + r) * K + kb + s * 8);
        }
        {
            int r = tid >> 2, s = tid & 3;
            *(uint4*)&Bs[r * 40 + s * 8] =
                *(const uint4*)(Bt + (size_t)(col0 + r) * K + kb + s * 8);
        }
        __syncthreads();

        short8 af[MT];
        #pragma unroll
        for (int mt = 0; mt < MT; ++mt)
            af[mt] = *(const short8*)&As[(w * 16 * MT + mt * 16 + l15) * 40 + q * 8];
        #pragma unroll
        for (int nt = 0; nt < 4; ++nt) {
            short8 bf = *(const short8*)&Bs[(nt * 16 + l15) * 40 + q * 8];
            #pragma unroll
            for (int mt = 0; mt < MT; ++mt)
                acc[mt][nt] = __builtin_amdgcn_mfma_f32_16x16x32_bf16(
                    af[mt], bf, acc[mt][nt], 0, 0, 0);
        }
        __syncthreads();
    }

    #pragma unroll
    for (int mt = 0; mt < MT; ++mt) {
        #pragma unroll
        for (int nt = 0; nt < 4; ++nt) {
            #pragma unroll
            for (int reg = 0; reg < 4; ++reg) {
                int row = row0 + w * 16 * MT + mt * 16 + q * 4 + reg;
                int col = col0 + nt * 16 + l15;
                float v = acc[mt][nt][reg] + bias[col];
                if (ACT == ACT_GELU) v = gelu_erf(v);
                if (RES) v += Rsd[(size_t)row * N + col];
                if (FOUT) C[(size_t)row * N + col] = v;
                if (BOUT) Cb[(size_t)row * N + col] = f2b(v);
            }
        }
    }
}

// ---------------------------------------------------------------------------
// Fused channel attention: o2 = sigmoid(relu(xl@ca1+b1)@ca2+b2) * xl
// ---------------------------------------------------------------------------
__global__ __launch_bounds__(256) void chanattn_kernel(
    const float* __restrict__ xl, const float* __restrict__ ca1w,
    const float* __restrict__ ca1b, const float* __restrict__ ca2w,
    const float* __restrict__ ca2b, float* __restrict__ o2)
{
    __shared__ float xs[256];
    __shared__ float sm16[16];
    size_t row = blockIdx.x;
    int tid = threadIdx.x;
    xs[tid] = xl[row * 256 + tid];
    __syncthreads();

    int h = tid >> 4, part = tid & 15;
    float p = 0.f;
    #pragma unroll
    for (int i = 0; i < 16; ++i)
        p += xs[part * 16 + i] * ca1w[(part * 16 + i) * 16 + h];
    p += __shfl_down(p, 8, 16);
    p += __shfl_down(p, 4, 16);
    p += __shfl_down(p, 2, 16);
    p += __shfl_down(p, 1, 16);
    if (part == 0) sm16[h] = fmaxf(p + ca1b[h], 0.0f);
    __syncthreads();

    float g = ca2b[tid];
    #pragma unroll
    for (int hh = 0; hh < 16; ++hh) g += sm16[hh] * ca2w[hh * 256 + tid];
    g = 1.0f / (1.0f + expf(-g));
    o2[row * 256 + tid] = g * xs[tid];
}

// ---------------------------------------------------------------------------
// mixed = sum_n softmax(node_w[:cnt]/0.01)[n] * feat_n   (fp32 + bf16 out)
// ---------------------------------------------------------------------------
__global__ __launch_bounds__(256) void mix_kernel(
    const float* p0, const float* p1, const float* p2, const float* p3,
    const float* p4, const float* p5, const float* p6, const float* p7,
    const float* __restrict__ node_w, int cnt,
    float* __restrict__ out, unsigned short* __restrict__ outb, int n)
{
    int i = blockIdx.x * 256 + threadIdx.x;
    if (i >= n) return;
    float w[8];
    float mx = -1e30f;
    for (int t = 0; t < cnt; ++t) { w[t] = node_w[t] * 100.0f; mx = fmaxf(mx, w[t]); }
    float s = 0.0f;
    for (int t = 0; t < cnt; ++t) { w[t] = expf(w[t] - mx); s += w[t]; }
    float inv = 1.0f / s;
    const float* ps[8] = {p0, p1, p2, p3, p4, p5, p6, p7};
    float v = 0.0f;
    for (int t = 0; t < cnt; ++t) v += w[t] * inv * ps[t][i];
    out[i] = v;
    outb[i] = f2b(v);
}

// ---------------------------------------------------------------------------
// Row LayerNorm -> bf16 output. One block per row.
// ---------------------------------------------------------------------------
__global__ __launch_bounds__(256) void ln_kernel(
    const float* __restrict__ in, unsigned short* __restrict__ outb,
    const float* __restrict__ g, const float* __restrict__ bb, int N)
{
    __shared__ float sm[4];
    size_t row = blockIdx.x;
    const float* xr = in + row * N;
    int lane = threadIdx.x & 63, wid = threadIdx.x >> 6;

    float s = 0.0f;
    for (int i = threadIdx.x; i < N; i += 256) s += xr[i];
    #pragma unroll
    for (int off = 32; off > 0; off >>= 1) s += __shfl_down(s, off, 64);
    if (lane == 0) sm[wid] = s;
    __syncthreads();
    float mu = (sm[0] + sm[1] + sm[2] + sm[3]) / N;
    __syncthreads();

    float s2 = 0.0f;
    for (int i = threadIdx.x; i < N; i += 256) { float d = xr[i] - mu; s2 += d * d; }
    #pragma unroll
    for (int off = 32; off > 0; off >>= 1) s2 += __shfl_down(s2, off, 64);
    if (lane == 0) sm[wid] = s2;
    __syncthreads();
    float var = (sm[0] + sm[1] + sm[2] + sm[3]) / N;
    float rstd = rsqrtf(var + 1e-5f);

    for (int i = threadIdx.x; i < N; i += 256)
        outb[row * N + i] = f2b((xr[i] - mu) * rstd * g[i] + bb[i]);
}

// ---------------------------------------------------------------------------
// MFMA flash attention. One block per (b, h, 128-query tile); 4 waves.
// Per 128-key tile: LN K -> f16 LDS, S = Q@K^T via mfma_f32_16x16x32_f16
// (K=16 zero-padded to 32), online softmax in C-layout regs, P -> per-wave
// LDS region -> A-frags, PV via mfma with V^T staged in LDS.
// Scores carry log2e (folded into Q scale); exponentials are native exp2.
// ---------------------------------------------------------------------------
__global__ __launch_bounds__(256) void attn_kernel(
    const float* __restrict__ qkv,   // [4096,768] q|k|v
    const float* __restrict__ nqg, const float* __restrict__ nqb,
    const float* __restrict__ nkg, const float* __restrict__ nkb,
    unsigned short* __restrict__ outb)   // [4096,256] bf16
{
    int qt = blockIdx.x, h = blockIdx.y, b = blockIdx.z;
    int tid = threadIdx.x;
    int w = tid >> 6, lane = tid & 63;
    int l15 = lane & 15, quad = lane >> 4;

    // rows padded: Qs/Kb 40 halves (80B, 16B-aligned, 2-way banks)
    // Vt/Ps 136 halves (272B, 16B-aligned)
    __shared__ __align__(16) _Float16 Qs[128 * 40];
    __shared__ __align__(16) _Float16 Kb[128 * 40];
    __shared__ __align__(16) _Float16 Vt[16 * 136];
    __shared__ __align__(16) _Float16 Ps[4][32 * 136];

    const float QSC = 0.25f * 1.44269504088896340736f;  // 1/sqrt(16)*log2(e)

    // ---- stage Q (LN -> f16) + zero the k=16..31 pads of Qs and Kb ----
    if (tid < 128) {
        int r = tid;
        const float* qp = qkv + ((size_t)(b * 1024 + qt * 128 + r)) * 768 + h * 16;
        float v[16];
        #pragma unroll
        for (int d4 = 0; d4 < 4; ++d4) {
            f32x4 t = *(const f32x4*)(qp + d4 * 4);
            v[d4*4+0]=t[0]; v[d4*4+1]=t[1]; v[d4*4+2]=t[2]; v[d4*4+3]=t[3];
        }
        float mu = 0.f;
        #pragma unroll
        for (int d = 0; d < 16; ++d) mu += v[d];
        mu *= (1.0f / 16.0f);
        float var = 0.f;
        #pragma unroll
        for (int d = 0; d < 16; ++d) { float t = v[d] - mu; var += t * t; }
        var *= (1.0f / 16.0f);
        float rstd = rsqrtf(var + 1e-5f);
        #pragma unroll
        for (int d4 = 0; d4 < 4; ++d4) {
            half4 t;
            #pragma unroll
            for (int e = 0; e < 4; ++e)
                t[e] = (_Float16)(((v[d4*4+e] - mu) * rstd * nqg[d4*4+e] + nqb[d4*4+e]) * QSC);
            *(half4*)&Qs[r * 40 + d4 * 4] = t;
        }
        half4 z = (half4){(_Float16)0, (_Float16)0, (_Float16)0, (_Float16)0};
        #pragma unroll
        for (int d4 = 4; d4 < 8; ++d4) {
            *(half4*)&Qs[r * 40 + d4 * 4] = z;
            *(half4*)&Kb[r * 40 + d4 * 4] = z;
        }
    }
    __syncthreads();

    // per-wave Q A-frags for its 32 queries (2 m-subtiles)
    half8 aq[2];
    aq[0] = *(const half8*)&Qs[(w * 32 + l15) * 40 + quad * 8];
    aq[1] = *(const half8*)&Qs[(w * 32 + 16 + l15) * 40 + quad * 8];

    float mst[2][4], lst[2][4];
    f32x4 acco[2];
    #pragma unroll
    for (int mi = 0; mi < 2; ++mi) {
        acco[mi] = (f32x4){0.f, 0.f, 0.f, 0.f};
        #pragma unroll
        for (int reg = 0; reg < 4; ++reg) { mst[mi][reg] = -1e30f; lst[mi][reg] = 0.f; }
    }

    for (int kt = 0; kt < 8; ++kt) {
        __syncthreads();   // previous iteration's readers done with Kb/Vt
        if (tid < 128) {
            int r = tid;
            const float* kp = qkv + ((size_t)(b * 1024 + kt * 128 + r)) * 768 + 256 + h * 16;
            float v[16];
            #pragma unroll
            for (int d4 = 0; d4 < 4; ++d4) {
                f32x4 t = *(const f32x4*)(kp + d4 * 4);
                v[d4*4+0]=t[0]; v[d4*4+1]=t[1]; v[d4*4+2]=t[2]; v[d4*4+3]=t[3];
            }
            float mu = 0.f;
            #pragma unroll
            for (int d = 0; d < 16; ++d) mu += v[d];
            mu *= (1.0f / 16.0f);
            float var = 0.f;
            #pragma unroll
            for (int d = 0; d < 16; ++d) { float t = v[d] - mu; var += t * t; }
            var *= (1.0f / 16.0f);
            float rstd = rsqrtf(var + 1e-5f);
            #pragma unroll
            for (int d4 = 0; d4 < 4; ++d4) {
                half4 t;
                #pragma unroll
                for (int e = 0; e < 4; ++e)
                    t[e] = (_Float16)((v[d4*4+e] - mu) * rstd * nkg[d4*4+e] + nkb[d4*4+e]);
                *(half4*)&Kb[r * 40 + d4 * 4] = t;
            }
        } else {
            int r = tid - 128;
            const float* vp = qkv + ((size_t)(b * 1024 + kt * 128 + r)) * 768 + 512 + h * 16;
            #pragma unroll
            for (int d = 0; d < 16; ++d)
                Vt[d * 136 + r] = (_Float16)vp[d];
        }
        __syncthreads();

        // ---- S-tile: 32 queries x 128 keys per wave ----
        f32x4 sacc[2][8];
        #pragma unroll
        for (int mi = 0; mi < 2; ++mi)
            #pragma unroll
            for (int ni = 0; ni < 8; ++ni)
                sacc[mi][ni] = (f32x4){0.f, 0.f, 0.f, 0.f};
        #pragma unroll
        for (int ni = 0; ni < 8; ++ni) {
            half8 bk = *(const half8*)&Kb[(ni * 16 + l15) * 40 + quad * 8];
            sacc[0][ni] = __builtin_amdgcn_mfma_f32_16x16x32_f16(aq[0], bk, sacc[0][ni], 0, 0, 0);
            sacc[1][ni] = __builtin_amdgcn_mfma_f32_16x16x32_f16(aq[1], bk, sacc[1][ni], 0, 0, 0);
        }

        // ---- online softmax (C-layout: row=quad*4+reg, col=ni*16+l15) ----
        float mnew[2][4];
        #pragma unroll
        for (int mi = 0; mi < 2; ++mi) {
            #pragma unroll
            for (int reg = 0; reg < 4; ++reg) {
                float rm = sacc[mi][0][reg];
                #pragma unroll
                for (int ni = 1; ni < 8; ++ni) rm = fmaxf(rm, sacc[mi][ni][reg]);
                rm = fmaxf(rm, __shfl_xor(rm, 1, 16));
                rm = fmaxf(rm, __shfl_xor(rm, 2, 16));
                rm = fmaxf(rm, __shfl_xor(rm, 4, 16));
                rm = fmaxf(rm, __shfl_xor(rm, 8, 16));
                float mn = fmaxf(mst[mi][reg], rm);
                float cor = exp2f(mst[mi][reg] - mn);
                lst[mi][reg] *= cor;
                acco[mi][reg] *= cor;
                mst[mi][reg] = mn;
                mnew[mi][reg] = mn;
            }
        }
        #pragma unroll
        for (int mi = 0; mi < 2; ++mi) {
            float lsum[4] = {0.f, 0.f, 0.f, 0.f};
            #pragma unroll
            for (int ni = 0; ni < 8; ++ni) {
                #pragma unroll
                for (int reg = 0; reg < 4; ++reg) {
                    float p = exp2f(sacc[mi][ni][reg] - mnew[mi][reg]);
                    lsum[reg] += p;
                    Ps[w][(mi * 16 + quad * 4 + reg) * 136 + ni * 16 + l15] = (_Float16)p;
                }
            }
            #pragma unroll
            for (int reg = 0; reg < 4; ++reg) {
                float ls = lsum[reg];
                ls += __shfl_xor(ls, 1, 16);
                ls += __shfl_xor(ls, 2, 16);
                ls += __shfl_xor(ls, 4, 16);
                ls += __shfl_xor(ls, 8, 16);
                lst[mi][reg] += ls;
            }
        }
        __syncthreads();   // P visible (cross-lane within wave; cheap)

        // ---- PV: O[32 x 16] += P[32 x 128] @ V[128 x 16] ----
        #pragma unroll
        for (int c = 0; c < 4; ++c) {
            half8 bv = *(const half8*)&Vt[l15 * 136 + quad * 8 + c * 32];
            half8 p0 = *(const half8*)&Ps[w][l15 * 136 + quad * 8 + c * 32];
            half8 p1 = *(const half8*)&Ps[w][(16 + l15) * 136 + quad * 8 + c * 32];
            acco[0] = __builtin_amdgcn_mfma_f32_16x16x32_f16(p0, bv, acco[0], 0, 0, 0);
            acco[1] = __builtin_amdgcn_mfma_f32_16x16x32_f16(p1, bv, acco[1], 0, 0, 0);
        }
    }

    // ---- write O (bf16) ----
    #pragma unroll
    for (int mi = 0; mi < 2; ++mi) {
        #pragma unroll
        for (int reg = 0; reg < 4; ++reg) {
            float o = acco[mi][reg] / lst[mi][reg];
            int row = b * 1024 + qt * 128 + w * 32 + mi * 16 + quad * 4 + reg;
            outb[(size_t)row * 256 + h * 16 + l15] = f2b(o);
        }
    }
}

// ---------------------------------------------------------------------------
static void wt_launch(const float* in, unsigned short* out, int K, int N,
                      hipStream_t s)
{
    wtrans_kernel<<<dim3(K / 32, N / 32), dim3(32, 8), 0, s>>>(in, out, K, N);
}

extern "C" void kernel_launch(void* const* d_in, const int* in_sizes, int n_in,
                              void* d_out, int out_size, void* d_ws, size_t ws_size,
                              hipStream_t stream)
{
    const float* x          = (const float*)d_in[0];
    const int*   mask_index = (const int*)  d_in[1];
    const float* Wp         = (const float*)d_in[2];
    const float* bp         = (const float*)d_in[3];
    const float* cls        = (const float*)d_in[4];
    const float* qkv_w      = (const float*)d_in[5];
    const float* qkv_b      = (const float*)d_in[6];
    const float* proj_w     = (const float*)d_in[7];
    const float* proj_b     = (const float*)d_in[8];
    const float* nq_g       = (const float*)d_in[9];
    const float* nq_b       = (const float*)d_in[10];
    const float* nk_g       = (const float*)d_in[11];
    const float* nk_b       = (const float*)d_in[12];
    const float* conv_w     = (const float*)d_in[13];
    const float* conv_b     = (const float*)d_in[14];
    const float* ca1_w      = (const float*)d_in[15];
    const float* ca1_b      = (const float*)d_in[16];
    const float* ca2_w      = (const float*)d_in[17];
    const float* ca2_b      = (const float*)d_in[18];
    const float* mlp1_w     = (const float*)d_in[19];
    const float* mlp1_b     = (const float*)d_in[20];
    const float* mlp2_w     = (const float*)d_in[21];
    const float* mlp2_b     = (const float*)d_in[22];
    const float* node_w     = (const float*)d_in[23];
    const float* ln0_g      = (const float*)d_in[24];
    const float* ln0_b      = (const float*)d_in[25];
    const float* h1_w       = (const float*)d_in[26];
    const float* h1_b       = (const float*)d_in[27];
    const float* ln1_g      = (const float*)d_in[28];
    const float* ln1_b      = (const float*)d_in[29];
    const float* h2_w       = (const float*)d_in[30];
    const float* h2_b       = (const float*)d_in[31];
    const float* ln2_g      = (const float*)d_in[32];
    const float* ln2_b      = (const float*)d_in[33];
    const float* h3_w       = (const float*)d_in[34];
    const float* h3_b       = (const float*)d_in[35];
    const float* pr_w       = (const float*)d_in[36];
    const float* pr_b       = (const float*)d_in[37];
    float* out = (float*)d_out;

    // ---- workspace layout ----
    char* base = (char*)d_ws;
    size_t off = 0;
    auto alloc = [&](size_t bytes) -> char* {
        char* p = base + off;
        off += (bytes + 255) & ~(size_t)255;
        return p;
    };
    const size_t RC = (size_t)RTOK * CDIM;
    float* F[5];
    unsigned short* Fb[5];
    for (int i = 0; i < 5; ++i) F[i] = (float*)alloc(RC * 4);
    for (int i = 0; i < 5; ++i) Fb[i] = (unsigned short*)alloc(RC * 2);
    float* O1  = (float*)alloc(RC * 4);
    float* O2  = (float*)alloc(RC * 4);
    float* O4  = (float*)alloc(RC * 4);
    float* MIX = (float*)alloc(RC * 4);
    unsigned short* MIXb = (unsigned short*)alloc(RC * 2);
    unsigned short* AOb  = (unsigned short*)alloc(RC * 2);
    float* BIGF = (float*)alloc((size_t)RTOK * 2048 * 4);
    unsigned short* MIDU = (unsigned short*)alloc((size_t)RTOK * 2048 * 2);
    unsigned short* L0b  = (unsigned short*)alloc(RC * 2);
    unsigned short* L2b  = (unsigned short*)alloc(RC * 2);
    unsigned short* H3b  = (unsigned short*)alloc((size_t)RTOK * 2048 * 2);
    // bf16 transposed weights
    unsigned short* convb = (unsigned short*)alloc((size_t)4 * 256 * 256 * 2);
    unsigned short* qkvb  = (unsigned short*)alloc((size_t)4 * 768 * 256 * 2);
    unsigned short* projb = (unsigned short*)alloc((size_t)4 * 256 * 256 * 2);
    unsigned short* mlp1b = (unsigned short*)alloc((size_t)4 * 1024 * 256 * 2);
    unsigned short* mlp2b = (unsigned short*)alloc((size_t)4 * 256 * 1024 * 2);
    unsigned short* h1b   = (unsigned short*)alloc((size_t)2048 * 256 * 2);
    unsigned short* h2b   = (unsigned short*)alloc((size_t)256 * 2048 * 2);
    unsigned short* h3b   = (unsigned short*)alloc((size_t)2048 * 256 * 2);
    unsigned short* prb   = (unsigned short*)alloc((size_t)512 * 2048 * 2);

    // ---- weight conversion ----
    for (int j = 0; j < 4; ++j) {
        wt_launch(conv_w + (size_t)j * 256 * 256,  convb + (size_t)j * 256 * 256,  256, 256,  stream);
        wt_launch(qkv_w  + (size_t)j * 256 * 768,  qkvb  + (size_t)j * 768 * 256,  256, 768,  stream);
        wt_launch(proj_w + (size_t)j * 256 * 256,  projb + (size_t)j * 256 * 256,  256, 256,  stream);
        wt_launch(mlp1_w + (size_t)j * 256 * 1024, mlp1b + (size_t)j * 1024 * 256, 256, 1024, stream);
        wt_launch(mlp2_w + (size_t)j * 1024 * 256, mlp2b + (size_t)j * 256 * 1024, 1024, 256, stream);
    }
    wt_launch(h1_w, h1b, 256, 2048,  stream);
    wt_launch(h2_w, h2b, 2048, 256,  stream);
    wt_launch(h3_w, h3b, 256, 2048,  stream);
    wt_launch(pr_w, prb, 2048, 512,  stream);

    // ---- embed ----
    embed_kernel<<<RTOK, 256, 0, stream>>>(x, mask_index, Wp, bp, cls, F[0], Fb[0]);

    // ---- 4 block iterations ----
    for (int j = 0; j < 4; ++j) {
        const float* xl = F[j];
        const unsigned short* xlb = Fb[j];
        gemm_mfma<1, ACT_GELU, false, true, false><<<dim3(4, 64), 256, 0, stream>>>(
            xlb, convb + (size_t)j * 256 * 256, conv_b + j * 256, nullptr,
            O1, nullptr, RTOK, 256, 256);
        chanattn_kernel<<<RTOK, 256, 0, stream>>>(
            xl, ca1_w + (size_t)j * 256 * 16, ca1_b + j * 16,
            ca2_w + (size_t)j * 16 * 256, ca2_b + j * 256, O2);
        gemm_mfma<2, ACT_GELU, false, false, true><<<dim3(16, 32), 256, 0, stream>>>(
            xlb, mlp1b + (size_t)j * 1024 * 256, mlp1_b + j * 1024, nullptr,
            nullptr, MIDU, RTOK, 1024, 256);
        gemm_mfma<1, ACT_NONE, false, true, false><<<dim3(4, 64), 256, 0, stream>>>(
            MIDU, mlp2b + (size_t)j * 256 * 1024, mlp2_b + j * 256, nullptr,
            O4, nullptr, RTOK, 256, 1024);
        const float* ps[8] = {nullptr, nullptr, nullptr, nullptr,
                              nullptr, nullptr, nullptr, nullptr};
        int cnt = 0;
        for (int t = 0; t <= j; ++t) ps[cnt++] = F[t];
        ps[cnt++] = O1; ps[cnt++] = O2; ps[cnt++] = F[j]; ps[cnt++] = O4;
        mix_kernel<<<(int)(RC / 256), 256, 0, stream>>>(
            ps[0], ps[1], ps[2], ps[3], ps[4], ps[5], ps[6], ps[7],
            node_w + j * 8, cnt, MIX, MIXb, (int)RC);
        gemm_mfma<2, ACT_NONE, false, true, false><<<dim3(12, 32), 256, 0, stream>>>(
            MIXb, qkvb + (size_t)j * 768 * 256, qkv_b + j * 768, nullptr,
            BIGF, nullptr, RTOK, 768, 256);
        attn_kernel<<<dim3(8, NHEAD, BSZ), 256, 0, stream>>>(
            BIGF, nq_g + j * 16, nq_b + j * 16, nk_g + j * 16, nk_b + j * 16, AOb);
        gemm_mfma<1, ACT_NONE, true, true, true><<<dim3(4, 64), 256, 0, stream>>>(
            AOb, projb + (size_t)j * 256 * 256, proj_b + j * 256, MIX,
            F[j + 1], Fb[j + 1], RTOK, 256, 256);
    }

    // ---- predict head ----
    ln_kernel<<<RTOK, 256, 0, stream>>>(F[4], L0b, ln0_g, ln0_b, 256);
    gemm_mfma<2, ACT_NONE, false, true, false><<<dim3(32, 32), 256, 0, stream>>>(
        L0b, h1b, h1_b, nullptr, BIGF, nullptr, RTOK, 2048, 256);
    ln_kernel<<<RTOK, 256, 0, stream>>>(BIGF, MIDU, ln1_g, ln1_b, 2048);
    gemm_mfma<1, ACT_NONE, false, true, false><<<dim3(4, 64), 256, 0, stream>>>(
        MIDU, h2b, h2_b, nullptr, MIX, nullptr, RTOK, 256, 2048);
    ln_kernel<<<RTOK, 256, 0, stream>>>(MIX, L2b, ln2_g, ln2_b, 256);
    gemm_mfma<2, ACT_NONE, false, false, true><<<dim3(32, 32), 256, 0, stream>>>(
        L2b, h3b, h3_b, nullptr, nullptr, H3b, RTOK, 2048, 256);
    gemm_mfma<1, ACT_NONE, false, true, false><<<dim3(8, 64), 256, 0, stream>>>(
        H3b, prb, pr_b, nullptr, out, nullptr, RTOK, 512, 2048);
}

// Round 6
// 882.898 us; speedup vs baseline: 4.2290x; 1.0313x over previous
//
#include <hip/hip_runtime.h>
#include <math.h>
#include <cstddef>

// ---- problem constants ----
#define RTOK 4096
#define CDIM 256
#define NHEAD 16
#define DHEAD 16
#define SEQ 1024
#define BSZ 4

#define ACT_NONE 0
#define ACT_GELU 1

typedef short short8 __attribute__((ext_vector_type(8)));
typedef float f32x4  __attribute__((ext_vector_type(4)));
typedef _Float16 half8 __attribute__((ext_vector_type(8)));
typedef _Float16 half4 __attribute__((ext_vector_type(4)));

__device__ __forceinline__ float gelu_erf(float x) {
    return 0.5f * x * (1.0f + erff(x * 0.70710678118654752f));
}
__device__ __forceinline__ unsigned short f2b(float f) {
    unsigned u = __float_as_uint(f);
    unsigned r = (u + 0x7FFFu + ((u >> 16) & 1u)) >> 16;
    return (unsigned short)r;
}

// ---------------------------------------------------------------------------
// Weight convert+transpose: in [K,N] fp32 -> out [N,K] bf16. 32x32 LDS tile.
// Batched over blockIdx.z with explicit per-layer strides.
// ---------------------------------------------------------------------------
__global__ __launch_bounds__(256) void wtrans_kernel(
    const float* __restrict__ in, unsigned short* __restrict__ out,
    int K, int N, long zin, long zout)
{
    in  += (size_t)blockIdx.z * zin;
    out += (size_t)blockIdx.z * zout;
    __shared__ float t[32][33];
    int kb = blockIdx.x * 32, nb = blockIdx.y * 32;
    int tx = threadIdx.x, ty = threadIdx.y;   // 32 x 8
    #pragma unroll
    for (int r = 0; r < 4; ++r) {
        int kk = ty * 4 + r;
        t[kk][tx] = in[(size_t)(kb + kk) * N + nb + tx];
    }
    __syncthreads();
    #pragma unroll
    for (int r = 0; r < 4; ++r) {
        int nn = ty * 4 + r;
        out[(size_t)(nb + nn) * K + kb + tx] = f2b(t[tx][nn]);
    }
}

// ---------------------------------------------------------------------------
// Fused patch-embed + pos-embed + cls + mask-gather (fp32 + bf16 outputs).
// ---------------------------------------------------------------------------
__global__ __launch_bounds__(256) void embed_kernel(
    const float* __restrict__ x, const int* __restrict__ mask_index,
    const float* __restrict__ Wp, const float* __restrict__ bp,
    const float* __restrict__ cls,
    float* __restrict__ out, unsigned short* __restrict__ outb)
{
    int row = blockIdx.x;
    int b = row >> 10;
    int c = threadIdx.x;
    int idx = mask_index[row];
    if (idx == 0) {
        float v = cls[c];
        out[(size_t)row * 256 + c] = v;
        outb[(size_t)row * 256 + c] = f2b(v);
        return;
    }
    int p  = idx - 1;
    int ph = p >> 6, pw = p & 63;

    __shared__ float xs[12];
    if (c < 12) {
        int ch = c >> 2, r = (c >> 1) & 1, q = c & 1;
        xs[c] = x[(((size_t)b * 3 + ch) * 128 + (ph * 2 + r)) * 128 + (pw * 2 + q)];
    }
    __syncthreads();

    float acc = bp[c];
    #pragma unroll
    for (int t = 0; t < 12; ++t) acc += xs[t] * Wp[c * 12 + t];

    int part = c >> 6, cc = c & 63;
    double omega = exp((double)cc * -0.14391156831212787);
    double posv  = (part < 2) ? (double)pw : (double)ph;
    double a     = posv * omega;
    double e     = ((part & 1) == 0) ? sin(a) : cos(a);
    float v = acc + (float)e;
    out[(size_t)row * 256 + c] = v;
    outb[(size_t)row * 256 + c] = f2b(v);
}

// ---------------------------------------------------------------------------
// bf16 MFMA GEMM with register-double-buffered staging.
// C[M,N] = act(A[M,K] @ Bt[N,K]^T + bias) (+Rsd)
// SPLIT: cols < N0 -> C fp32 (stride N0, bias), cols >= N0 -> Cb bf16
//        (stride N-N0, bias1). Used for fused conv||mlp1.
// ---------------------------------------------------------------------------
template<int MT, int ACT, bool RES, bool FOUT, bool BOUT, bool SPLIT>
__global__ __launch_bounds__(256) void gemm_mfma(
    const unsigned short* __restrict__ A, const unsigned short* __restrict__ Bt,
    const float* __restrict__ bias, const float* __restrict__ bias1,
    const float* __restrict__ Rsd,
    float* __restrict__ C, unsigned short* __restrict__ Cb,
    int M, int N, int K, int N0)
{
    constexpr int BM = 64 * MT;
    __shared__ __align__(16) unsigned short As[BM * 40];
    __shared__ __align__(16) unsigned short Bs[64 * 40];
    int tid = threadIdx.x;
    int w = tid >> 6, lane = tid & 63;
    int l15 = lane & 15, q = lane >> 4;
    int row0 = blockIdx.y * BM, col0 = blockIdx.x * 64;

    f32x4 acc[MT][4];
    #pragma unroll
    for (int mt = 0; mt < MT; ++mt)
        #pragma unroll
        for (int nt = 0; nt < 4; ++nt)
            acc[mt][nt] = (f32x4){0.f, 0.f, 0.f, 0.f};

    // prefetch kb=0 into registers
    uint4 pa[MT], pb;
    #pragma unroll
    for (int t = 0; t < MT; ++t) {
        int sid = tid + t * 256, r = sid >> 2, s = sid & 3;
        pa[t] = *(const uint4*)(A + (size_t)(row0 + r) * K + s * 8);
    }
    {
        int r = tid >> 2, s = tid & 3;
        pb = *(const uint4*)(Bt + (size_t)(col0 + r) * K + s * 8);
    }

    for (int kb = 0; kb < K; kb += 32) {
        #pragma unroll
        for (int t = 0; t < MT; ++t) {
            int sid = tid + t * 256, r = sid >> 2, s = sid & 3;
            *(uint4*)&As[r * 40 + s * 8] = pa[t];
        }
        {
            int r = tid >> 2, s = tid & 3;
            *(uint4*)&Bs[r * 40 + s * 8] = pb;
        }
        __syncthreads();

        if (kb + 32 < K) {   // issue next slab's loads; overlap with MFMA phase
            #pragma unroll
            for (int t = 0; t < MT; ++t) {
                int sid = tid + t * 256, r = sid >> 2, s = sid & 3;
                pa[t] = *(const uint4*)(A + (size_t)(row0 + r) * K + kb + 32 + s * 8);
            }
            int r = tid >> 2, s = tid & 3;
            pb = *(const uint4*)(Bt + (size_t)(col0 + r) * K + kb + 32 + s * 8);
        }

        short8 af[MT];
        #pragma unroll
        for (int mt = 0; mt < MT; ++mt)
            af[mt] = *(const short8*)&As[(w * 16 * MT + mt * 16 + l15) * 40 + q * 8];
        #pragma unroll
        for (int nt = 0; nt < 4; ++nt) {
            short8 bf = *(const short8*)&Bs[(nt * 16 + l15) * 40 + q * 8];
            #pragma unroll
            for (int mt = 0; mt < MT; ++mt)
                acc[mt][nt] = __builtin_amdgcn_mfma_f32_16x16x32_bf16(
                    af[mt], bf, acc[mt][nt], 0, 0, 0);
        }
        __syncthreads();
    }

    #pragma unroll
    for (int mt = 0; mt < MT; ++mt) {
        #pragma unroll
        for (int nt = 0; nt < 4; ++nt) {
            #pragma unroll
            for (int reg = 0; reg < 4; ++reg) {
                int row = row0 + w * 16 * MT + mt * 16 + q * 4 + reg;
                int col = col0 + nt * 16 + l15;
                if (SPLIT) {
                    float v = acc[mt][nt][reg] +
                              (col < N0 ? bias[col] : bias1[col - N0]);
                    if (ACT == ACT_GELU) v = gelu_erf(v);
                    if (col < N0) C[(size_t)row * N0 + col] = v;
                    else Cb[(size_t)row * (N - N0) + (col - N0)] = f2b(v);
                } else {
                    float v = acc[mt][nt][reg] + bias[col];
                    if (ACT == ACT_GELU) v = gelu_erf(v);
                    if (RES) v += Rsd[(size_t)row * N + col];
                    if (FOUT) C[(size_t)row * N + col] = v;
                    if (BOUT) Cb[(size_t)row * N + col] = f2b(v);
                }
            }
        }
    }
}

// ---------------------------------------------------------------------------
// Fused channel attention: o2 = sigmoid(relu(xl@ca1+b1)@ca2+b2) * xl
// ---------------------------------------------------------------------------
__global__ __launch_bounds__(256) void chanattn_kernel(
    const float* __restrict__ xl, const float* __restrict__ ca1w,
    const float* __restrict__ ca1b, const float* __restrict__ ca2w,
    const float* __restrict__ ca2b, float* __restrict__ o2)
{
    __shared__ float xs[256];
    __shared__ float sm16[16];
    size_t row = blockIdx.x;
    int tid = threadIdx.x;
    xs[tid] = xl[row * 256 + tid];
    __syncthreads();

    int h = tid >> 4, part = tid & 15;
    float p = 0.f;
    #pragma unroll
    for (int i = 0; i < 16; ++i)
        p += xs[part * 16 + i] * ca1w[(part * 16 + i) * 16 + h];
    p += __shfl_down(p, 8, 16);
    p += __shfl_down(p, 4, 16);
    p += __shfl_down(p, 2, 16);
    p += __shfl_down(p, 1, 16);
    if (part == 0) sm16[h] = fmaxf(p + ca1b[h], 0.0f);
    __syncthreads();

    float g = ca2b[tid];
    #pragma unroll
    for (int hh = 0; hh < 16; ++hh) g += sm16[hh] * ca2w[hh * 256 + tid];
    g = 1.0f / (1.0f + expf(-g));
    o2[row * 256 + tid] = g * xs[tid];
}

// ---------------------------------------------------------------------------
// mixed = sum_n softmax(node_w[:cnt]/0.01)[n] * feat_n   (fp32 + bf16 out)
// ---------------------------------------------------------------------------
__global__ __launch_bounds__(256) void mix_kernel(
    const float* p0, const float* p1, const float* p2, const float* p3,
    const float* p4, const float* p5, const float* p6, const float* p7,
    const float* __restrict__ node_w, int cnt,
    float* __restrict__ out, unsigned short* __restrict__ outb, int n)
{
    int i = blockIdx.x * 256 + threadIdx.x;
    if (i >= n) return;
    float w[8];
    float mx = -1e30f;
    for (int t = 0; t < cnt; ++t) { w[t] = node_w[t] * 100.0f; mx = fmaxf(mx, w[t]); }
    float s = 0.0f;
    for (int t = 0; t < cnt; ++t) { w[t] = expf(w[t] - mx); s += w[t]; }
    float inv = 1.0f / s;
    const float* ps[8] = {p0, p1, p2, p3, p4, p5, p6, p7};
    float v = 0.0f;
    for (int t = 0; t < cnt; ++t) v += w[t] * inv * ps[t][i];
    out[i] = v;
    outb[i] = f2b(v);
}

// ---------------------------------------------------------------------------
// Row LayerNorm -> bf16 output. One block per row.
// ---------------------------------------------------------------------------
__global__ __launch_bounds__(256) void ln_kernel(
    const float* __restrict__ in, unsigned short* __restrict__ outb,
    const float* __restrict__ g, const float* __restrict__ bb, int N)
{
    __shared__ float sm[4];
    size_t row = blockIdx.x;
    const float* xr = in + row * N;
    int lane = threadIdx.x & 63, wid = threadIdx.x >> 6;

    float s = 0.0f;
    for (int i = threadIdx.x; i < N; i += 256) s += xr[i];
    #pragma unroll
    for (int off = 32; off > 0; off >>= 1) s += __shfl_down(s, off, 64);
    if (lane == 0) sm[wid] = s;
    __syncthreads();
    float mu = (sm[0] + sm[1] + sm[2] + sm[3]) / N;
    __syncthreads();

    float s2 = 0.0f;
    for (int i = threadIdx.x; i < N; i += 256) { float d = xr[i] - mu; s2 += d * d; }
    #pragma unroll
    for (int off = 32; off > 0; off >>= 1) s2 += __shfl_down(s2, off, 64);
    if (lane == 0) sm[wid] = s2;
    __syncthreads();
    float var = (sm[0] + sm[1] + sm[2] + sm[3]) / N;
    float rstd = rsqrtf(var + 1e-5f);

    for (int i = threadIdx.x; i < N; i += 256)
        outb[row * N + i] = f2b((xr[i] - mu) * rstd * g[i] + bb[i]);
}

// ---------------------------------------------------------------------------
// MFMA flash attention, S^T form. One block per (b, h, 128-query tile).
// S^T = K@Q^T so the C-layout puts 4 consecutive KEYS in a lane's regs:
//  - P stores become half4/ds_write_b64 (was 64 scalar b16)
//  - softmax reductions need only shfl_xor 16/32
//  - Ps is wave-private: no barrier between softmax and PV.
// O rescale needs per-q redistribution (q=quad*4+reg) via 4 bpermutes.
// ---------------------------------------------------------------------------
__global__ __launch_bounds__(256) void attn_kernel(
    const float* __restrict__ qkv,   // [4096,768] q|k|v
    const float* __restrict__ nqg, const float* __restrict__ nqb,
    const float* __restrict__ nkg, const float* __restrict__ nkb,
    unsigned short* __restrict__ outb)   // [4096,256] bf16
{
    int qt = blockIdx.x, h = blockIdx.y, b = blockIdx.z;
    int tid = threadIdx.x;
    int w = tid >> 6, lane = tid & 63;
    int l15 = lane & 15, quad = lane >> 4;

    __shared__ __align__(16) _Float16 Qs[128 * 40];
    __shared__ __align__(16) _Float16 Kb[128 * 40];
    __shared__ __align__(16) _Float16 Vt[16 * 136];
    __shared__ __align__(16) _Float16 Ps[4][32 * 136];

    const float QSC = 0.25f * 1.44269504088896340736f;  // 1/sqrt(16)*log2(e)

    // ---- stage Q (LN -> f16) + zero k=16..31 pads of Qs and Kb ----
    if (tid < 128) {
        int r = tid;
        const float* qp = qkv + ((size_t)(b * 1024 + qt * 128 + r)) * 768 + h * 16;
        float v[16];
        #pragma unroll
        for (int d4 = 0; d4 < 4; ++d4) {
            f32x4 t = *(const f32x4*)(qp + d4 * 4);
            v[d4*4+0]=t[0]; v[d4*4+1]=t[1]; v[d4*4+2]=t[2]; v[d4*4+3]=t[3];
        }
        float mu = 0.f;
        #pragma unroll
        for (int d = 0; d < 16; ++d) mu += v[d];
        mu *= (1.0f / 16.0f);
        float var = 0.f;
        #pragma unroll
        for (int d = 0; d < 16; ++d) { float t = v[d] - mu; var += t * t; }
        var *= (1.0f / 16.0f);
        float rstd = rsqrtf(var + 1e-5f);
        #pragma unroll
        for (int d4 = 0; d4 < 4; ++d4) {
            half4 t;
            #pragma unroll
            for (int e = 0; e < 4; ++e)
                t[e] = (_Float16)(((v[d4*4+e] - mu) * rstd * nqg[d4*4+e] + nqb[d4*4+e]) * QSC);
            *(half4*)&Qs[r * 40 + d4 * 4] = t;
        }
        half4 z = (half4){(_Float16)0, (_Float16)0, (_Float16)0, (_Float16)0};
        #pragma unroll
        for (int d4 = 4; d4 < 8; ++d4) {
            *(half4*)&Qs[r * 40 + d4 * 4] = z;
            *(half4*)&Kb[r * 40 + d4 * 4] = z;
        }
    }
    __syncthreads();

    // Q B-frags: B[n=q_local][k=d] for the wave's two 16-query subtiles
    half8 bq[2];
    bq[0] = *(const half8*)&Qs[(w * 32 + l15) * 40 + quad * 8];
    bq[1] = *(const half8*)&Qs[(w * 32 + 16 + l15) * 40 + quad * 8];

    float mst[2] = {-1e30f, -1e30f};   // per q = l15 (uniform across quads)
    float lst[2] = {0.f, 0.f};
    f32x4 acco[2];                     // O C-layout: row=q=quad*4+reg, col=d=l15
    acco[0] = (f32x4){0.f, 0.f, 0.f, 0.f};
    acco[1] = (f32x4){0.f, 0.f, 0.f, 0.f};

    for (int kt = 0; kt < 8; ++kt) {
        __syncthreads();   // previous iteration's readers done with Kb/Vt
        if (tid < 128) {
            int r = tid;
            const float* kp = qkv + ((size_t)(b * 1024 + kt * 128 + r)) * 768 + 256 + h * 16;
            float v[16];
            #pragma unroll
            for (int d4 = 0; d4 < 4; ++d4) {
                f32x4 t = *(const f32x4*)(kp + d4 * 4);
                v[d4*4+0]=t[0]; v[d4*4+1]=t[1]; v[d4*4+2]=t[2]; v[d4*4+3]=t[3];
            }
            float mu = 0.f;
            #pragma unroll
            for (int d = 0; d < 16; ++d) mu += v[d];
            mu *= (1.0f / 16.0f);
            float var = 0.f;
            #pragma unroll
            for (int d = 0; d < 16; ++d) { float t = v[d] - mu; var += t * t; }
            var *= (1.0f / 16.0f);
            float rstd = rsqrtf(var + 1e-5f);
            #pragma unroll
            for (int d4 = 0; d4 < 4; ++d4) {
                half4 t;
                #pragma unroll
                for (int e = 0; e < 4; ++e)
                    t[e] = (_Float16)((v[d4*4+e] - mu) * rstd * nkg[d4*4+e] + nkb[d4*4+e]);
                *(half4*)&Kb[r * 40 + d4 * 4] = t;
            }
        } else {
            int r = tid - 128;
            const float* vp = qkv + ((size_t)(b * 1024 + kt * 128 + r)) * 768 + 512 + h * 16;
            #pragma unroll
            for (int d = 0; d < 16; ++d)
                Vt[d * 136 + r] = (_Float16)vp[d];
        }
        __syncthreads();

        // ---- S^T tile: 128 keys x 32 queries per wave ----
        f32x4 sacc[2][8];
        #pragma unroll
        for (int ni = 0; ni < 8; ++ni) {
            half8 ak = *(const half8*)&Kb[(ni * 16 + l15) * 40 + quad * 8];
            sacc[0][ni] = __builtin_amdgcn_mfma_f32_16x16x32_f16(
                ak, bq[0], (f32x4){0.f, 0.f, 0.f, 0.f}, 0, 0, 0);
            sacc[1][ni] = __builtin_amdgcn_mfma_f32_16x16x32_f16(
                ak, bq[1], (f32x4){0.f, 0.f, 0.f, 0.f}, 0, 0, 0);
        }
        // sacc[mi][ni][reg] = S[q = w*32+mi*16+l15][kk = kt*128+ni*16+quad*4+reg]

        #pragma unroll
        for (int mi = 0; mi < 2; ++mi) {
            // row max over this kt's 128 keys for q=l15
            float rm = sacc[mi][0][0];
            #pragma unroll
            for (int ni = 0; ni < 8; ++ni)
                #pragma unroll
                for (int reg = 0; reg < 4; ++reg)
                    rm = fmaxf(rm, sacc[mi][ni][reg]);
            rm = fmaxf(rm, __shfl_xor(rm, 16, 64));
            rm = fmaxf(rm, __shfl_xor(rm, 32, 64));
            float mn  = fmaxf(mst[mi], rm);
            float cor = exp2f(mst[mi] - mn);
            mst[mi] = mn;
            lst[mi] *= cor;
            // redistribute cor to O layout (q = quad*4+reg)
            #pragma unroll
            for (int reg = 0; reg < 4; ++reg) {
                float cR = __shfl(cor, (lane & 48) + quad * 4 + reg, 64);
                acco[mi][reg] *= cR;
            }
            // p = exp2(s-mn), packed b64 stores, in-lane lsum
            float lsum = 0.f;
            #pragma unroll
            for (int ni = 0; ni < 8; ++ni) {
                half4 ph;
                #pragma unroll
                for (int reg = 0; reg < 4; ++reg) {
                    float p = exp2f(sacc[mi][ni][reg] - mn);
                    lsum += p;
                    ph[reg] = (_Float16)p;
                }
                *(half4*)&Ps[w][(mi * 16 + l15) * 136 + ni * 16 + quad * 4] = ph;
            }
            lsum += __shfl_xor(lsum, 16, 64);
            lsum += __shfl_xor(lsum, 32, 64);
            lst[mi] += lsum;
        }
        // Ps[w] is wave-private: no barrier needed before PV (lgkmcnt only)

        // ---- PV: O[32q x 16d] += P[32q x 128kk] @ V[128kk x 16d] ----
        #pragma unroll
        for (int c = 0; c < 4; ++c) {
            half8 bv = *(const half8*)&Vt[l15 * 136 + c * 32 + quad * 8];
            half8 p0 = *(const half8*)&Ps[w][l15 * 136 + c * 32 + quad * 8];
            half8 p1 = *(const half8*)&Ps[w][(16 + l15) * 136 + c * 32 + quad * 8];
            acco[0] = __builtin_amdgcn_mfma_f32_16x16x32_f16(p0, bv, acco[0], 0, 0, 0);
            acco[1] = __builtin_amdgcn_mfma_f32_16x16x32_f16(p1, bv, acco[1], 0, 0, 0);
        }
    }

    // ---- write O (bf16); l needs redistribution to q=quad*4+reg ----
    #pragma unroll
    for (int mi = 0; mi < 2; ++mi) {
        #pragma unroll
        for (int reg = 0; reg < 4; ++reg) {
            float lR = __shfl(lst[mi], (lane & 48) + quad * 4 + reg, 64);
            float o = acco[mi][reg] / lR;
            int row = b * 1024 + qt * 128 + w * 32 + mi * 16 + quad * 4 + reg;
            outb[(size_t)row * 256 + h * 16 + l15] = f2b(o);
        }
    }
}

// ---------------------------------------------------------------------------
static void wt_launch(const float* in, unsigned short* out, int K, int N,
                      int Z, long zin, long zout, hipStream_t s)
{
    wtrans_kernel<<<dim3(K / 32, N / 32, Z), dim3(32, 8), 0, s>>>(
        in, out, K, N, zin, zout);
}

extern "C" void kernel_launch(void* const* d_in, const int* in_sizes, int n_in,
                              void* d_out, int out_size, void* d_ws, size_t ws_size,
                              hipStream_t stream)
{
    const float* x          = (const float*)d_in[0];
    const int*   mask_index = (const int*)  d_in[1];
    const float* Wp         = (const float*)d_in[2];
    const float* bp         = (const float*)d_in[3];
    const float* cls        = (const float*)d_in[4];
    const float* qkv_w      = (const float*)d_in[5];
    const float* qkv_b      = (const float*)d_in[6];
    const float* proj_w     = (const float*)d_in[7];
    const float* proj_b     = (const float*)d_in[8];
    const float* nq_g       = (const float*)d_in[9];
    const float* nq_b       = (const float*)d_in[10];
    const float* nk_g       = (const float*)d_in[11];
    const float* nk_b       = (const float*)d_in[12];
    const float* conv_w     = (const float*)d_in[13];
    const float* conv_b     = (const float*)d_in[14];
    const float* ca1_w      = (const float*)d_in[15];
    const float* ca1_b      = (const float*)d_in[16];
    const float* ca2_w      = (const float*)d_in[17];
    const float* ca2_b      = (const float*)d_in[18];
    const float* mlp1_w     = (const float*)d_in[19];
    const float* mlp1_b     = (const float*)d_in[20];
    const float* mlp2_w     = (const float*)d_in[21];
    const float* mlp2_b     = (const float*)d_in[22];
    const float* node_w     = (const float*)d_in[23];
    const float* ln0_g      = (const float*)d_in[24];
    const float* ln0_b      = (const float*)d_in[25];
    const float* h1_w       = (const float*)d_in[26];
    const float* h1_b       = (const float*)d_in[27];
    const float* ln1_g      = (const float*)d_in[28];
    const float* ln1_b      = (const float*)d_in[29];
    const float* h2_w       = (const float*)d_in[30];
    const float* h2_b       = (const float*)d_in[31];
    const float* ln2_g      = (const float*)d_in[32];
    const float* ln2_b      = (const float*)d_in[33];
    const float* h3_w       = (const float*)d_in[34];
    const float* h3_b       = (const float*)d_in[35];
    const float* pr_w       = (const float*)d_in[36];
    const float* pr_b       = (const float*)d_in[37];
    float* out = (float*)d_out;

    // ---- workspace layout ----
    char* base = (char*)d_ws;
    size_t off = 0;
    auto alloc = [&](size_t bytes) -> char* {
        char* p = base + off;
        off += (bytes + 255) & ~(size_t)255;
        return p;
    };
    const size_t RC = (size_t)RTOK * CDIM;
    float* F[5];
    unsigned short* Fb[5];
    for (int i = 0; i < 5; ++i) F[i] = (float*)alloc(RC * 4);
    for (int i = 0; i < 5; ++i) Fb[i] = (unsigned short*)alloc(RC * 2);
    float* O1  = (float*)alloc(RC * 4);
    float* O2  = (float*)alloc(RC * 4);
    float* O4  = (float*)alloc(RC * 4);
    float* MIX = (float*)alloc(RC * 4);
    unsigned short* MIXb = (unsigned short*)alloc(RC * 2);
    unsigned short* AOb  = (unsigned short*)alloc(RC * 2);
    float* BIGF = (float*)alloc((size_t)RTOK * 2048 * 4);
    unsigned short* MIDU = (unsigned short*)alloc((size_t)RTOK * 2048 * 2);
    unsigned short* L0b  = (unsigned short*)alloc(RC * 2);
    unsigned short* L2b  = (unsigned short*)alloc(RC * 2);
    unsigned short* H3b  = (unsigned short*)alloc((size_t)RTOK * 2048 * 2);
    // bf16 transposed weights; conv||mlp1 concatenated to [1280,256] per layer
    unsigned short* cm1b  = (unsigned short*)alloc((size_t)4 * 1280 * 256 * 2);
    unsigned short* qkvb  = (unsigned short*)alloc((size_t)4 * 768 * 256 * 2);
    unsigned short* projb = (unsigned short*)alloc((size_t)4 * 256 * 256 * 2);
    unsigned short* mlp2b = (unsigned short*)alloc((size_t)4 * 256 * 1024 * 2);
    unsigned short* h1b   = (unsigned short*)alloc((size_t)2048 * 256 * 2);
    unsigned short* h2b   = (unsigned short*)alloc((size_t)256 * 2048 * 2);
    unsigned short* h3b   = (unsigned short*)alloc((size_t)2048 * 256 * 2);
    unsigned short* prb   = (unsigned short*)alloc((size_t)512 * 2048 * 2);

    // ---- weight conversion (z-batched over the 4 layers) ----
    wt_launch(conv_w, cm1b,              256, 256,  4, 256 * 256,  1280 * 256, stream);
    wt_launch(mlp1_w, cm1b + 256 * 256,  256, 1024, 4, 256 * 1024, 1280 * 256, stream);
    wt_launch(qkv_w,  qkvb,  256, 768,  4, 256 * 768,  768 * 256,  stream);
    wt_launch(proj_w, projb, 256, 256,  4, 256 * 256,  256 * 256,  stream);
    wt_launch(mlp2_w, mlp2b, 1024, 256, 4, 1024 * 256, 256 * 1024, stream);
    wt_launch(h1_w, h1b, 256, 2048, 1, 0, 0, stream);
    wt_launch(h2_w, h2b, 2048, 256, 1, 0, 0, stream);
    wt_launch(h3_w, h3b, 256, 2048, 1, 0, 0, stream);
    wt_launch(pr_w, prb, 2048, 512, 1, 0, 0, stream);

    // ---- embed ----
    embed_kernel<<<RTOK, 256, 0, stream>>>(x, mask_index, Wp, bp, cls, F[0], Fb[0]);

    // ---- 4 block iterations ----
    for (int j = 0; j < 4; ++j) {
        const float* xl = F[j];
        const unsigned short* xlb = Fb[j];
        // fused o1 = gelu(xl@conv) [fp32] || t4 = gelu(xl@mlp1) [bf16]
        gemm_mfma<2, ACT_GELU, false, false, false, true><<<dim3(20, 32), 256, 0, stream>>>(
            xlb, cm1b + (size_t)j * 1280 * 256, conv_b + j * 256, mlp1_b + j * 1024,
            nullptr, O1, MIDU, RTOK, 1280, 256, 256);
        chanattn_kernel<<<RTOK, 256, 0, stream>>>(
            xl, ca1_w + (size_t)j * 256 * 16, ca1_b + j * 16,
            ca2_w + (size_t)j * 16 * 256, ca2_b + j * 256, O2);
        gemm_mfma<1, ACT_NONE, false, true, false, false><<<dim3(4, 64), 256, 0, stream>>>(
            MIDU, mlp2b + (size_t)j * 256 * 1024, mlp2_b + j * 256, nullptr, nullptr,
            O4, nullptr, RTOK, 256, 1024, 0);
        const float* ps[8] = {nullptr, nullptr, nullptr, nullptr,
                              nullptr, nullptr, nullptr, nullptr};
        int cnt = 0;
        for (int t = 0; t <= j; ++t) ps[cnt++] = F[t];
        ps[cnt++] = O1; ps[cnt++] = O2; ps[cnt++] = F[j]; ps[cnt++] = O4;
        mix_kernel<<<(int)(RC / 256), 256, 0, stream>>>(
            ps[0], ps[1], ps[2], ps[3], ps[4], ps[5], ps[6], ps[7],
            node_w + j * 8, cnt, MIX, MIXb, (int)RC);
        gemm_mfma<2, ACT_NONE, false, true, false, false><<<dim3(12, 32), 256, 0, stream>>>(
            MIXb, qkvb + (size_t)j * 768 * 256, qkv_b + j * 768, nullptr, nullptr,
            BIGF, nullptr, RTOK, 768, 256, 0);
        attn_kernel<<<dim3(8, NHEAD, BSZ), 256, 0, stream>>>(
            BIGF, nq_g + j * 16, nq_b + j * 16, nk_g + j * 16, nk_b + j * 16, AOb);
        gemm_mfma<1, ACT_NONE, true, true, true, false><<<dim3(4, 64), 256, 0, stream>>>(
            AOb, projb + (size_t)j * 256 * 256, proj_b + j * 256, nullptr, MIX,
            F[j + 1], Fb[j + 1], RTOK, 256, 256, 0);
    }

    // ---- predict head ----
    ln_kernel<<<RTOK, 256, 0, stream>>>(F[4], L0b, ln0_g, ln0_b, 256);
    gemm_mfma<2, ACT_NONE, false, true, false, false><<<dim3(32, 32), 256, 0, stream>>>(
        L0b, h1b, h1_b, nullptr, nullptr, BIGF, nullptr, RTOK, 2048, 256, 0);
    ln_kernel<<<RTOK, 256, 0, stream>>>(BIGF, MIDU, ln1_g, ln1_b, 2048);
    gemm_mfma<1, ACT_NONE, false, true, false, false><<<dim3(4, 64), 256, 0, stream>>>(
        MIDU, h2b, h2_b, nullptr, nullptr, MIX, nullptr, RTOK, 256, 2048, 0);
    ln_kernel<<<RTOK, 256, 0, stream>>>(MIX, L2b, ln2_g, ln2_b, 256);
    gemm_mfma<2, ACT_NONE, false, false, true, false><<<dim3(32, 32), 256, 0, stream>>>(
        L2b, h3b, h3_b, nullptr, nullptr, nullptr, H3b, RTOK, 2048, 256, 0);
    gemm_mfma<1, ACT_NONE, false, true, false, false><<<dim3(8, 64), 256, 0, stream>>>(
        H3b, prb, pr_b, nullptr, nullptr, out, nullptr, RTOK, 512, 2048, 0);
}